// Round 16
// baseline (401.373 us; speedup 1.0000x reference)
//
#include <hip/hip_runtime.h>
#include <hip/hip_bf16.h>
#include <cstdint>
#include <cstddef>

// SGM fused pipeline, MI355X gfx950.
// Shapes: B=32 L=64 N=1024 D=512 C=8192 WS=3 NH=16 HD=32 HID=1024
// Encoder rows M=12288 (side*6144 + pos*3 + w), cross rows 4096 (side*2048+pos).
// Residual stream X and Q are bf16 (threshold headroom ~20000x).
// GEMM: round-12 proven gemm128 (ring-3, counted vmcnt) + supertile-XCD mapping:
// each XCD owns a column of 4x8-block supertiles -> its B-panels stay L2-resident.

typedef __attribute__((ext_vector_type(8))) short s16x8;
typedef __attribute__((ext_vector_type(8))) unsigned short u16x8;
typedef __attribute__((ext_vector_type(4))) unsigned short u16x4;
typedef __attribute__((ext_vector_type(4))) float f32x4;

__device__ __forceinline__ float b2f(unsigned short u) {
  union { unsigned int i; float f; } c; c.i = ((unsigned int)u) << 16; return c.f;
}
__device__ __forceinline__ unsigned short f2b(float f) {
  union { float f; unsigned int i; } c; c.f = f;
  unsigned int x = c.i;
  return (unsigned short)((x + 0x7FFFu + ((x >> 16) & 1u)) >> 16); // RNE, no NaN in this net
}

// async global->LDS, 16B per lane; LDS dest is wave-uniform base + lane*16
#define GLOAD16(gp, lp)                                                        \
  __builtin_amdgcn_global_load_lds(                                           \
      (const __attribute__((address_space(1))) void*)(gp),                    \
      (__attribute__((address_space(3))) void*)(lp), 16, 0, 0)

// ---------------- fused fp32 -> bf16 convert for ALL weights (1 launch) ----------------
__global__ void cvt_all(const float* __restrict__ s0, const float* __restrict__ s1,
                        const float* __restrict__ s2, const float* __restrict__ s3,
                        const float* __restrict__ s4, const float* __restrict__ s5,
                        const float* __restrict__ s6, const float* __restrict__ s7,
                        unsigned short* __restrict__ d) {
  int c = blockIdx.x * 256 + threadIdx.x;
  if (c >= 1835008) return;
  int e = c * 4;
  const float* sp; int off;
  if      (e <  786432) { sp = s0; off = 0; }
  else if (e < 1048576) { sp = s1; off =  786432; }
  else if (e < 1572864) { sp = s2; off = 1048576; }
  else if (e < 2097152) { sp = s3; off = 1572864; }
  else if (e < 2359296) { sp = s4; off = 2097152; }
  else if (e < 2883584) { sp = s5; off = 2359296; }
  else if (e < 3145728) { sp = s6; off = 2883584; }
  else                  { sp = s7; off = 3145728; }
  float4 v = *(const float4*)(sp + (e - off));
  u16x4 o; o[0] = f2b(v.x); o[1] = f2b(v.y); o[2] = f2b(v.z); o[3] = f2b(v.w);
  *(u16x4*)(d + e) = o;
}

// ---------------- FUSED embed + token + LN1 (wave per row; id is row-uniform) -----------
__global__ __launch_bounds__(256) void embed_ln1(const int* __restrict__ targets,
    const int* __restrict__ pad_p, const float* __restrict__ ce,
    const float* __restrict__ ltok, const float* __restrict__ rtok,
    const float* __restrict__ g, const float* __restrict__ bb,
    unsigned short* __restrict__ xb, unsigned short* __restrict__ a1) {
  int row = blockIdx.x * 4 + (threadIdx.x >> 6);   // 0..12287
  int lane = threadIdx.x & 63;
  int side = row >= 6144;
  int rem = row - side * 6144;
  int pos = rem / 3, w = rem - pos * 3;
  int b = pos >> 6, l = pos & 63;
  int id;
  if (!side) { int ti = l + w - 3; id = (ti >= 0) ? targets[(b << 6) + ti] : *pad_p; }
  else       { int ti = l + w + 1; id = (ti < 64) ? targets[(b << 6) + ti] : *pad_p; }
  const float* cp = ce + (size_t)id * 512 + lane * 8;
  const float* tp = (side ? rtok : ltok) + lane * 8;
  float4 c0 = ((const float4*)cp)[0], c1 = ((const float4*)cp)[1];
  float4 t0 = ((const float4*)tp)[0], t1 = ((const float4*)tp)[1];
  float vv[8] = {c0.x + t0.x, c0.y + t0.y, c0.z + t0.z, c0.w + t0.w,
                 c1.x + t1.x, c1.y + t1.y, c1.z + t1.z, c1.w + t1.w};
  int c = lane * 8;
  u16x8 xo;
#pragma unroll
  for (int j = 0; j < 8; ++j) xo[j] = f2b(vv[j]);
  *(u16x8*)(xb + (size_t)row * 512 + c) = xo;
  float s = 0.f, ss = 0.f;
#pragma unroll
  for (int j = 0; j < 8; ++j) { s += vv[j]; ss += vv[j] * vv[j]; }
#pragma unroll
  for (int o = 1; o < 64; o <<= 1) { s += __shfl_xor(s, o); ss += __shfl_xor(ss, o); }
  float mean = s * (1.0f / 512.0f);
  float var = ss * (1.0f / 512.0f) - mean * mean;
  float inv = rsqrtf(var + 1e-5f);
  u16x8 o8;
#pragma unroll
  for (int j = 0; j < 8; ++j) o8[j] = f2b((vv[j] - mean) * inv * g[c + j] + bb[c + j]);
  *(u16x8*)(a1 + (size_t)row * 512 + c) = o8;
}

// ---------------- LayerNorm (D=512 -> bf16 out), one wave per row; INBF: input dtype ----
template<int INBF>
__global__ __launch_bounds__(256) void ln_rows(const void* __restrict__ in,
    const float* __restrict__ g, const float* __restrict__ b,
    unsigned short* __restrict__ out, int M) {
  int row = blockIdx.x * 4 + (threadIdx.x >> 6);
  int lane = threadIdx.x & 63;
  float vv[8];
  if (INBF) {
    u16x8 v8 = *(const u16x8*)((const unsigned short*)in + (size_t)row * 512 + lane * 8);
#pragma unroll
    for (int j = 0; j < 8; ++j) vv[j] = b2f(v8[j]);
  } else {
    const float* rp = (const float*)in + (size_t)row * 512;
    float4 v0 = ((const float4*)rp)[lane * 2];
    float4 v1 = ((const float4*)rp)[lane * 2 + 1];
    vv[0] = v0.x; vv[1] = v0.y; vv[2] = v0.z; vv[3] = v0.w;
    vv[4] = v1.x; vv[5] = v1.y; vv[6] = v1.z; vv[7] = v1.w;
  }
  float s = 0.f, ss = 0.f;
#pragma unroll
  for (int j = 0; j < 8; ++j) { s += vv[j]; ss += vv[j] * vv[j]; }
#pragma unroll
  for (int o = 1; o < 64; o <<= 1) { s += __shfl_xor(s, o); ss += __shfl_xor(ss, o); }
  float mean = s * (1.0f / 512.0f);
  float var = ss * (1.0f / 512.0f) - mean * mean;
  float inv = rsqrtf(var + 1e-5f);
  int c = lane * 8;
  u16x8 o8;
#pragma unroll
  for (int j = 0; j < 8; ++j) o8[j] = f2b((vv[j] - mean) * inv * g[c + j] + b[c + j]);
  *(u16x8*)(out + (size_t)row * 512 + c) = o8;
}

// ---------------- FUSED mean over WS=3 + LNq (wave per position) ----------------
__global__ __launch_bounds__(256) void mean3_lnq(const unsigned short* __restrict__ x,
    const float* __restrict__ g, const float* __restrict__ bb,
    float* __restrict__ enc, unsigned short* __restrict__ lnq) {
  int p = blockIdx.x * 4 + (threadIdx.x >> 6);   // 0..4095
  int lane = threadIdx.x & 63;
  int c = lane * 8;
  u16x8 a = *(const u16x8*)(x + ((size_t)(p * 3 + 0) * 512 + c));
  u16x8 b = *(const u16x8*)(x + ((size_t)(p * 3 + 1) * 512 + c));
  u16x8 d = *(const u16x8*)(x + ((size_t)(p * 3 + 2) * 512 + c));
  float vv[8];
#pragma unroll
  for (int j = 0; j < 8; ++j) vv[j] = (b2f(a[j]) + b2f(b[j]) + b2f(d[j])) * (1.0f / 3.0f);
  float4 e0, e1;
  e0.x = vv[0]; e0.y = vv[1]; e0.z = vv[2]; e0.w = vv[3];
  e1.x = vv[4]; e1.y = vv[5]; e1.z = vv[6]; e1.w = vv[7];
  float* ep = enc + (size_t)p * 512 + c;
  ((float4*)ep)[0] = e0; ((float4*)ep)[1] = e1;
  float s = 0.f, ss = 0.f;
#pragma unroll
  for (int j = 0; j < 8; ++j) { s += vv[j]; ss += vv[j] * vv[j]; }
#pragma unroll
  for (int o = 1; o < 64; o <<= 1) { s += __shfl_xor(s, o); ss += __shfl_xor(ss, o); }
  float mean = s * (1.0f / 512.0f);
  float var = ss * (1.0f / 512.0f) - mean * mean;
  float inv = rsqrtf(var + 1e-5f);
  u16x8 o8;
#pragma unroll
  for (int j = 0; j < 8; ++j) o8[j] = f2b((vv[j] - mean) * inv * g[c + j] + bb[c + j]);
  *(u16x8*)(lnq + (size_t)p * 512 + c) = o8;
}

// ======== shared epilogue (wide stores; swapped-operand C layout) ========
template<int RES, int GELU, int OUTBF, int KVT>
__device__ __forceinline__ void epi_store(f32x4 v, int row, int col,
    const float* __restrict__ bias, const void* __restrict__ res,
    void* __restrict__ outp, int N) {
  f32x4 b4 = *(const f32x4*)(bias + col);
  v += b4;
  if (GELU) {
#pragma unroll
    for (int r = 0; r < 4; ++r)
      v[r] = 0.5f * v[r] * (1.0f + erff(v[r] * 0.70710678118654752f));
  }
  if (RES == 1) v += *(const f32x4*)((const float*)res + (size_t)row * N + col);
  if (RES == 2) {
    u16x4 r4 = *(const u16x4*)((const unsigned short*)res + (size_t)row * N + col);
#pragma unroll
    for (int r = 0; r < 4; ++r) v[r] += b2f(r4[r]);
  }
  if (KVT) {
    // row = b*1024 + n_vis ; col<512 -> K head block (contig dd), col>=512 -> V^T
    int bb = row >> 10, nn = row & 1023;
    unsigned short* Kp = (unsigned short*)outp;
    unsigned short* VpT = Kp + 16777216u;
    if (col < 512) {
      int hh = col >> 5, dd = col & 31;
      u16x4 o4;
#pragma unroll
      for (int r = 0; r < 4; ++r) o4[r] = f2b(v[r]);
      *(u16x4*)(Kp + (((size_t)(bb * 16 + hh)) * 1024 + nn) * 32 + dd) = o4;
    } else {
      int cc = col - 512, hh = cc >> 5, dd = cc & 31;
#pragma unroll
      for (int r = 0; r < 4; ++r)
        VpT[(((size_t)(bb * 16 + hh)) * 32 + dd + r) * 1024 + nn] = f2b(v[r]);
    }
  } else if (OUTBF) {
    u16x4 o4;
#pragma unroll
    for (int r = 0; r < 4; ++r) o4[r] = f2b(v[r]);
    *(u16x4*)((unsigned short*)outp + (size_t)row * N + col) = o4;
  } else {
    *(f32x4*)((float*)outp + (size_t)row * N + col) = v;
  }
}

// ---------------- bf16 MFMA GEMM, 128x128, BK=32, 3-slot ring (round-12, proven) -------
// + supertile-XCD mapping: supertiles of ST_M=4 x ST_N blocks; supertile s -> XCD s%8,
// so each XCD's B-panels stay L2-resident across its supertiles (nSTx==8 aligns the
// supertile COLUMN with the XCD -> B fetched ~once per XCD). Bijective; falls back to
// the proven col-fastest+XCD swizzle when divisibility fails.
template<int RES, int GELU, int OUTBF, int KVT>
__global__ __launch_bounds__(256) void gemm128(
    const unsigned short* __restrict__ A, const unsigned short* __restrict__ Bt,
    const float* __restrict__ bias, const void* __restrict__ res,
    void* __restrict__ outp, int M, int N, int K) {
  __shared__ unsigned short sA[3][4096];
  __shared__ unsigned short sB[3][4096];
  const int tid = threadIdx.x;
  const int nbx = gridDim.x, nby = gridDim.y;
  const int nwg = nbx * nby;
  int id = blockIdx.y * nbx + blockIdx.x;
  int bm, bn;
  const int ST_N = ((nbx & 7) == 0) ? 8 : (((nbx & 3) == 0) ? 4 : 0);
  int mapped = 0;
  if (ST_N && (nby & 3) == 0) {
    const int nSTx = nbx / ST_N, nSTy = nby >> 2;
    const int nST = nSTx * nSTy;
    if ((nST & 7) == 0) {
      const int bpst = ST_N << 2;          // blocks per supertile
      const int xcd = id & 7, rank = id >> 3;
      const int sSub = rank / bpst, j = rank - sSub * bpst;
      const int s = sSub * 8 + xcd;        // supertile index; XCD-aligned column
      const int sx = s % nSTx, sy = s / nSTx;
      const int jn = j % ST_N, jm = j / ST_N;
      bm = (sy * 4 + jm) * 128;
      bn = (sx * ST_N + jn) * 128;
      mapped = 1;
    }
  }
  if (!mapped) {
    if ((nwg & 7) == 0) id = (id & 7) * (nwg >> 3) + (id >> 3);
    bm = (id / nbx) * 128; bn = (id % nbx) * 128;
  }
  const int wave = tid >> 6, lane = tid & 63;
  const int wr = (wave >> 1) * 64, wc = (wave & 1) * 64;
  const int lrow = lane & 15, g = lane >> 4;
  f32x4 acc[4][4] = {};
  const int xoff = (((((lrow & 1) << 2) | g) ^ ((lrow >> 1) & 7)) << 3);
  const int baseA = ((wr >> 1) + (lrow >> 1)) * 64 + xoff;
  const int baseB = ((wc >> 1) + (lrow >> 1)) * 64 + xoff;
  const int slot8 = (tid & 7) ^ ((tid >> 3) & 7);
  const int srow = ((tid >> 3) << 1) + (slot8 >> 2);
  const int scol = (slot8 & 3) << 3;
  const unsigned short* gA = A + (size_t)(bm + srow) * K + scol;
  const unsigned short* gB = Bt + (size_t)(bn + srow) * K + scol;
  const int NT = K >> 5;

#define STG(slot, kt)                                                          \
  { _Pragma("unroll")                                                          \
    for (int i = 0; i < 2; ++i) {                                              \
      GLOAD16(gA + (size_t)(i * 64) * K + (kt) * 32, &sA[slot][i * 2048 + wave * 512]); \
      GLOAD16(gB + (size_t)(i * 64) * K + (kt) * 32, &sB[slot][i * 2048 + wave * 512]); \
    } }

  STG(0, 0);
  STG(1, 1);
  int sl = 0;
  for (int t = 0; t < NT; ++t) {
    if (t < NT - 1) asm volatile("s_waitcnt vmcnt(4)" ::: "memory");
    else            asm volatile("s_waitcnt vmcnt(0)" ::: "memory");
    __builtin_amdgcn_s_barrier();
    __builtin_amdgcn_sched_barrier(0);
    if (t + 2 < NT) {
      int sl2 = sl - 1; if (sl2 < 0) sl2 = 2;
      STG(sl2, t + 2);
    }
    s16x8 av[4], bv[4];
#pragma unroll
    for (int m = 0; m < 4; ++m) av[m] = *(const s16x8*)&sA[sl][baseA + m * 512];
#pragma unroll
    for (int n = 0; n < 4; ++n) bv[n] = *(const s16x8*)&sB[sl][baseB + n * 512];
    __builtin_amdgcn_s_setprio(1);
#pragma unroll
    for (int m = 0; m < 4; ++m)
#pragma unroll
      for (int n = 0; n < 4; ++n)
        acc[m][n] = __builtin_amdgcn_mfma_f32_16x16x32_bf16(bv[n], av[m], acc[m][n], 0, 0, 0);
    __builtin_amdgcn_s_setprio(0);
    asm volatile("s_waitcnt lgkmcnt(0)" ::: "memory");
    sl = (sl == 2) ? 0 : sl + 1;
  }
#undef STG

  const int orow_ = bm + wr + lrow;
  const int ocol_ = bn + wc + g * 4;
#pragma unroll
  for (int m = 0; m < 4; ++m)
#pragma unroll
    for (int n = 0; n < 4; ++n)
      epi_store<RES, GELU, OUTBF, KVT>(acc[m][n], orow_ + m * 16, ocol_ + n * 16,
                                       bias, res, outp, N);
}

// ---------------- windowed (WS=3) attention, thread per (side-pos, head, q-row) ----------------
__global__ __launch_bounds__(256) void winattn(const unsigned short* __restrict__ qkv,
                                               unsigned short* __restrict__ o) {
  int g = blockIdx.x * 256 + threadIdx.x;
  if (g >= 4096 * 48) return;
  int i = g % 3;
  int t = g / 3;
  int h = t & 15;
  int sp = t >> 4;
  const unsigned short* base = qkv + (size_t)sp * 4608 + h * 32;
  float qv[32];
  {
    const u16x8* qp = (const u16x8*)(base + (size_t)i * 1536);
#pragma unroll
    for (int c = 0; c < 4; ++c) {
      u16x8 v = qp[c];
#pragma unroll
      for (int j = 0; j < 8; ++j) qv[c * 8 + j] = b2f(v[j]);
    }
  }
  float s[3];
#pragma unroll
  for (int j3 = 0; j3 < 3; ++j3) {
    const u16x8* kp = (const u16x8*)(base + (size_t)j3 * 1536 + 512);
    float acc = 0.f;
#pragma unroll
    for (int c = 0; c < 4; ++c) {
      u16x8 v = kp[c];
#pragma unroll
      for (int j = 0; j < 8; ++j) acc += qv[c * 8 + j] * b2f(v[j]);
    }
    s[j3] = acc * 0.17677669529663687f;
  }
  float mx = fmaxf(s[0], fmaxf(s[1], s[2]));
  float e0 = __expf(s[0] - mx), e1 = __expf(s[1] - mx), e2 = __expf(s[2] - mx);
  float inv = 1.0f / (e0 + e1 + e2);
  float a0 = e0 * inv, a1 = e1 * inv, a2 = e2 * inv;
  unsigned short* op = o + (size_t)(sp * 3 + i) * 512 + h * 32;
  const u16x8* v0p = (const u16x8*)(base + 1024);
  const u16x8* v1p = (const u16x8*)(base + 1536 + 1024);
  const u16x8* v2p = (const u16x8*)(base + 3072 + 1024);
#pragma unroll
  for (int c = 0; c < 4; ++c) {
    u16x8 x0 = v0p[c], x1 = v1p[c], x2 = v2p[c];
    u16x8 ov;
#pragma unroll
    for (int j = 0; j < 8; ++j)
      ov[j] = f2b(a0 * b2f(x0[j]) + a1 * b2f(x1[j]) + a2 * b2f(x2[j]));
    *(u16x8*)(op + c * 8) = ov;
  }
}

// ---------------- cross attention, MFMA flash style; BOTH sides per (b,h) block ----------------
__global__ __launch_bounds__(512) void crossattn_mfma(const unsigned short* __restrict__ q,
    const unsigned short* __restrict__ Kp, const unsigned short* __restrict__ VpT,
    unsigned short* __restrict__ o) {
  __shared__ unsigned short Plds[8][2][16 * 40];
  const int bh = blockIdx.x;
  const int b = bh >> 4, h = bh & 15;
  const int tid = threadIdx.x;
  const int w = tid >> 6, lane = tid & 63;
  const int side = w >> 2, wsub = w & 3;
  const int ql = lane & 15, g = lane >> 4;
  const int qrow = side * 2048 + b * 64 + wsub * 16 + ql;
  const float SC = 0.17677669529663687f;
  s16x8 qf;
  {
    u16x8 qv8 = *(const u16x8*)(q + (size_t)qrow * 512 + h * 32 + g * 8);
#pragma unroll
    for (int j = 0; j < 8; ++j) qf[j] = (short)f2b(b2f(qv8[j]) * SC);
  }
  const unsigned short* kbase = Kp + ((size_t)(b * 16 + h) * 1024) * 32;
  const unsigned short* vbase = VpT + ((size_t)(b * 16 + h) * 32) * 1024;
  f32x4 oacc0 = {}, oacc1 = {};
  float m_run = -1e30f, l_part = 0.f;
  for (int kv0 = 0; kv0 < 1024; kv0 += 32) {
    const int pp = (kv0 >> 5) & 1;
    s16x8 kf0 = *(const s16x8*)(kbase + (size_t)(kv0 + ql) * 32 + g * 8);
    s16x8 kf1 = *(const s16x8*)(kbase + (size_t)(kv0 + 16 + ql) * 32 + g * 8);
    f32x4 z = {0.f, 0.f, 0.f, 0.f};
    f32x4 s0 = __builtin_amdgcn_mfma_f32_16x16x32_bf16(kf0, qf, z, 0, 0, 0);
    f32x4 s1 = __builtin_amdgcn_mfma_f32_16x16x32_bf16(kf1, qf, z, 0, 0, 0);
    float cm = fmaxf(fmaxf(fmaxf(s0[0], s0[1]), fmaxf(s0[2], s0[3])),
                     fmaxf(fmaxf(s1[0], s1[1]), fmaxf(s1[2], s1[3])));
    cm = fmaxf(cm, __shfl_xor(cm, 16));
    cm = fmaxf(cm, __shfl_xor(cm, 32));
    float m_new = fmaxf(m_run, cm);
    float corr = __expf(m_run - m_new);
    m_run = m_new;
    float p0[4], p1[4], ps = 0.f;
#pragma unroll
    for (int r = 0; r < 4; ++r) {
      p0[r] = __expf(s0[r] - m_new);
      p1[r] = __expf(s1[r] - m_new);
      ps += p0[r] + p1[r];
    }
    l_part = l_part * corr + ps;
    oacc0 *= corr; oacc1 *= corr;
    u16x4 w0, w1;
#pragma unroll
    for (int r = 0; r < 4; ++r) { w0[r] = f2b(p0[r]); w1[r] = f2b(p1[r]); }
    *(u16x4*)&Plds[w][pp][ql * 40 + g * 4] = w0;
    *(u16x4*)&Plds[w][pp][ql * 40 + 16 + g * 4] = w1;
    __syncthreads();
    s16x8 pf = *(const s16x8*)&Plds[w][pp][ql * 40 + g * 8];
    s16x8 vf0 = *(const s16x8*)(vbase + (size_t)ql * 1024 + kv0 + g * 8);
    s16x8 vf1 = *(const s16x8*)(vbase + (size_t)(16 + ql) * 1024 + kv0 + g * 8);
    oacc0 = __builtin_amdgcn_mfma_f32_16x16x32_bf16(vf0, pf, oacc0, 0, 0, 0);
    oacc1 = __builtin_amdgcn_mfma_f32_16x16x32_bf16(vf1, pf, oacc1, 0, 0, 0);
  }
  float lf = l_part;
  lf += __shfl_xor(lf, 16);
  lf += __shfl_xor(lf, 32);
  float inv = 1.0f / lf;
  unsigned short* op = o + (size_t)qrow * 512 + h * 32;
  u16x4 ov0, ov1;
#pragma unroll
  for (int r = 0; r < 4; ++r) {
    ov0[r] = f2b(oacc0[r] * inv);
    ov1[r] = f2b(oacc1[r] * inv);
  }
  *(u16x4*)(op + g * 4) = ov0;
  *(u16x4*)(op + 16 + g * 4) = ov1;
}

// ---------------- targets pass-through (output 2) ----------------
__global__ void tail_targets(const int* __restrict__ t, float* __restrict__ out) {
  int i = blockIdx.x * 256 + threadIdx.x;
  if (i < 2048) out[33554432 + i] = (float)t[i];
}

extern "C" void kernel_launch(void* const* d_in, const int* in_sizes, int n_in,
                              void* d_out, int out_size, void* d_ws, size_t ws_size,
                              hipStream_t stream) {
  const float* visual   = (const float*)d_in[0];
  const int*   targets  = (const int*)d_in[1];
  const int*   pad_p    = (const int*)d_in[2];
  const float* char_emb = (const float*)d_in[3];
  const float* ln1_g = (const float*)d_in[4];
  const float* ln1_b = (const float*)d_in[5];
  const float* in_proj_w = (const float*)d_in[6];
  const float* in_proj_b = (const float*)d_in[7];
  const float* out_w = (const float*)d_in[8];
  const float* out_b = (const float*)d_in[9];
  const float* fc1_w = (const float*)d_in[10];
  const float* fc1_b = (const float*)d_in[11];
  const float* fc2_w = (const float*)d_in[12];
  const float* fc2_b = (const float*)d_in[13];
  const float* ln2_g = (const float*)d_in[14];
  const float* ln2_b = (const float*)d_in[15];
  const float* ltok  = (const float*)d_in[16];
  const float* rtok  = (const float*)d_in[17];
  const float* q_w   = (const float*)d_in[18];
  const float* q_b   = (const float*)d_in[19];
  const float* kv_w  = (const float*)d_in[20];
  const float* kv_b  = (const float*)d_in[21];
  const float* proj_w = (const float*)d_in[22];
  const float* proj_b = (const float*)d_in[23];
  const float* lnq_g = (const float*)d_in[24];
  const float* lnq_b = (const float*)d_in[25];
  const float* lnkv_g = (const float*)d_in[26];
  const float* lnkv_b = (const float*)d_in[27];
  const float* head_w = (const float*)d_in[28];
  const float* head_b = (const float*)d_in[29];

  // workspace layout (bytes); Kp+VpT (bf16, 67MB) alias the dead encoder region
  char* ws = (char*)d_ws;
  unsigned short* W    = (unsigned short*)ws;                    // 14,680,064 B weights bf16
  unsigned short* XB   = (unsigned short*)(ws + 14680064ull);    // 12,582,912 B x bf16 12288x512
  unsigned short* KP   = (unsigned short*)(ws + 14680064ull);    // alias: 33,554,432 B Kp + 33,554,432 B VpT
  unsigned short* A1   = (unsigned short*)(ws + 39845888ull);    // 12,582,912 B bf16 12288x512
  unsigned short* B1   = (unsigned short*)(ws + 52428800ull);    // 25,165,824 B bf16 12288x1024
  unsigned short* QKV  = (unsigned short*)(ws + 77594624ull);    // 37,748,736 B bf16 12288x1536
  float*          ENC  = (float*)(ws + 115343360ull);            //  8,388,608 B fp32 4096x512
  unsigned short* VIS  = (unsigned short*)(ws + 123731968ull);   // 33,554,432 B bf16 32768x512
  unsigned short* Q    = (unsigned short*)(ws + 157286400ull);   //  4,194,304 B bf16 4096x512
  unsigned short* OC   = (unsigned short*)(ws + 165675008ull);   //  4,194,304 B bf16 4096x512
  unsigned short* FEAT = (unsigned short*)(ws + 169869312ull);   //  4,194,304 B bf16 4096x512
  unsigned short* LNQ  = (unsigned short*)(ws + 174063616ull);   //  4,194,304 B bf16 4096x512
  unsigned short* VPT  = KP + 16777216u;

  unsigned short* Wip   = W;
  unsigned short* Wout  = W + 786432;
  unsigned short* Wfc1  = W + 1048576;
  unsigned short* Wfc2  = W + 1572864;
  unsigned short* Wq    = W + 2097152;
  unsigned short* Wkv   = W + 2359296;
  unsigned short* Wproj = W + 2883584;
  unsigned short* Whead = W + 3145728;

  // one fused convert for all 8 weight matrices (1,835,008 float4 chunks)
  cvt_all<<<dim3(7168), dim3(256), 0, stream>>>(in_proj_w, out_w, fc1_w, fc2_w,
                                                q_w, kv_w, proj_w, head_w, W);

  // ---- encoders (left+right batched, M=12288) ----
  embed_ln1<<<dim3(3072), dim3(256), 0, stream>>>(targets, pad_p, char_emb, ltok, rtok,
                                                  ln1_g, ln1_b, XB, A1);
  gemm128<0,0,1,0><<<dim3(12, 96), dim3(256), 0, stream>>>(A1, Wip, in_proj_b, nullptr, QKV, 12288, 1536, 512);
  winattn<<<dim3(768), dim3(256), 0, stream>>>(QKV, B1);
  gemm128<2,0,1,0><<<dim3(4, 96), dim3(256), 0, stream>>>(B1, Wout, out_b, XB, XB, 12288, 512, 512);
  ln_rows<1><<<dim3(3072), dim3(256), 0, stream>>>(XB, ln2_g, ln2_b, A1, 12288);
  gemm128<0,1,1,0><<<dim3(8, 96), dim3(256), 0, stream>>>(A1, Wfc1, fc1_b, nullptr, B1, 12288, 1024, 512);
  gemm128<2,0,1,0><<<dim3(4, 96), dim3(256), 0, stream>>>(B1, Wfc2, fc2_b, XB, XB, 12288, 512, 1024);
  mean3_lnq<<<dim3(1024), dim3(256), 0, stream>>>(XB, lnq_g, lnq_b, ENC, LNQ);

  // ---- cross attention (kv shared by both sides; encoder buffers now dead) ----
  ln_rows<0><<<dim3(8192), dim3(256), 0, stream>>>(visual, lnkv_g, lnkv_b, VIS, 32768);
  gemm128<0,0,1,1><<<dim3(8, 256), dim3(256), 0, stream>>>(VIS, Wkv, kv_b, nullptr, KP, 32768, 1024, 512);
  gemm128<0,0,1,0><<<dim3(4, 32), dim3(256), 0, stream>>>(LNQ, Wq, q_b, nullptr, Q, 4096, 512, 512);
  crossattn_mfma<<<dim3(512), dim3(512), 0, stream>>>(Q, KP, VPT, OC);
  gemm128<1,0,1,0><<<dim3(4, 32), dim3(256), 0, stream>>>(OC, Wproj, proj_b, ENC, FEAT, 4096, 512, 512);

  // ---- head -> d_out (rows 0..2047 = sgm_left, 2048..4095 = sgm_right) ----
  gemm128<0,0,0,0><<<dim3(64, 32), dim3(256), 0, stream>>>(FEAT, Whead, head_b, nullptr, (float*)d_out, 4096, 8192, 512);
  tail_targets<<<dim3(8), dim3(256), 0, stream>>>(targets, (float*)d_out);
}

// Round 17
// 380.557 us; speedup vs baseline: 1.0547x; 1.0547x over previous
//
#include <hip/hip_runtime.h>
#include <hip/hip_bf16.h>
#include <cstdint>
#include <cstddef>

// SGM fused pipeline, MI355X gfx950.
// Shapes: B=32 L=64 N=1024 D=512 C=8192 WS=3 NH=16 HD=32 HID=1024
// Encoder rows M=12288 (side*6144 + pos*3 + w), cross rows 4096 (side*2048+pos).
// Residual stream X and Q are bf16 (threshold headroom ~20000x).
// GEMM: round-12 proven gemm128 (ring-3, counted vmcnt), col-fastest+XCD swizzle
// (supertile map r16: null), __launch_bounds__(256,3) to unlock 3 blocks/CU.

typedef __attribute__((ext_vector_type(8))) short s16x8;
typedef __attribute__((ext_vector_type(8))) unsigned short u16x8;
typedef __attribute__((ext_vector_type(4))) unsigned short u16x4;
typedef __attribute__((ext_vector_type(4))) float f32x4;

__device__ __forceinline__ float b2f(unsigned short u) {
  union { unsigned int i; float f; } c; c.i = ((unsigned int)u) << 16; return c.f;
}
__device__ __forceinline__ unsigned short f2b(float f) {
  union { float f; unsigned int i; } c; c.f = f;
  unsigned int x = c.i;
  return (unsigned short)((x + 0x7FFFu + ((x >> 16) & 1u)) >> 16); // RNE, no NaN in this net
}

// async global->LDS, 16B per lane; LDS dest is wave-uniform base + lane*16
#define GLOAD16(gp, lp)                                                        \
  __builtin_amdgcn_global_load_lds(                                           \
      (const __attribute__((address_space(1))) void*)(gp),                    \
      (__attribute__((address_space(3))) void*)(lp), 16, 0, 0)

// ---------------- fused fp32 -> bf16 convert for ALL weights (1 launch) ----------------
__global__ void cvt_all(const float* __restrict__ s0, const float* __restrict__ s1,
                        const float* __restrict__ s2, const float* __restrict__ s3,
                        const float* __restrict__ s4, const float* __restrict__ s5,
                        const float* __restrict__ s6, const float* __restrict__ s7,
                        unsigned short* __restrict__ d) {
  int c = blockIdx.x * 256 + threadIdx.x;
  if (c >= 1835008) return;
  int e = c * 4;
  const float* sp; int off;
  if      (e <  786432) { sp = s0; off = 0; }
  else if (e < 1048576) { sp = s1; off =  786432; }
  else if (e < 1572864) { sp = s2; off = 1048576; }
  else if (e < 2097152) { sp = s3; off = 1572864; }
  else if (e < 2359296) { sp = s4; off = 2097152; }
  else if (e < 2883584) { sp = s5; off = 2359296; }
  else if (e < 3145728) { sp = s6; off = 2883584; }
  else                  { sp = s7; off = 3145728; }
  float4 v = *(const float4*)(sp + (e - off));
  u16x4 o; o[0] = f2b(v.x); o[1] = f2b(v.y); o[2] = f2b(v.z); o[3] = f2b(v.w);
  *(u16x4*)(d + e) = o;
}

// ---------------- FUSED embed + token + LN1 (wave per row; id is row-uniform) -----------
__global__ __launch_bounds__(256) void embed_ln1(const int* __restrict__ targets,
    const int* __restrict__ pad_p, const float* __restrict__ ce,
    const float* __restrict__ ltok, const float* __restrict__ rtok,
    const float* __restrict__ g, const float* __restrict__ bb,
    unsigned short* __restrict__ xb, unsigned short* __restrict__ a1) {
  int row = blockIdx.x * 4 + (threadIdx.x >> 6);   // 0..12287
  int lane = threadIdx.x & 63;
  int side = row >= 6144;
  int rem = row - side * 6144;
  int pos = rem / 3, w = rem - pos * 3;
  int b = pos >> 6, l = pos & 63;
  int id;
  if (!side) { int ti = l + w - 3; id = (ti >= 0) ? targets[(b << 6) + ti] : *pad_p; }
  else       { int ti = l + w + 1; id = (ti < 64) ? targets[(b << 6) + ti] : *pad_p; }
  const float* cp = ce + (size_t)id * 512 + lane * 8;
  const float* tp = (side ? rtok : ltok) + lane * 8;
  float4 c0 = ((const float4*)cp)[0], c1 = ((const float4*)cp)[1];
  float4 t0 = ((const float4*)tp)[0], t1 = ((const float4*)tp)[1];
  float vv[8] = {c0.x + t0.x, c0.y + t0.y, c0.z + t0.z, c0.w + t0.w,
                 c1.x + t1.x, c1.y + t1.y, c1.z + t1.z, c1.w + t1.w};
  int c = lane * 8;
  u16x8 xo;
#pragma unroll
  for (int j = 0; j < 8; ++j) xo[j] = f2b(vv[j]);
  *(u16x8*)(xb + (size_t)row * 512 + c) = xo;
  float s = 0.f, ss = 0.f;
#pragma unroll
  for (int j = 0; j < 8; ++j) { s += vv[j]; ss += vv[j] * vv[j]; }
#pragma unroll
  for (int o = 1; o < 64; o <<= 1) { s += __shfl_xor(s, o); ss += __shfl_xor(ss, o); }
  float mean = s * (1.0f / 512.0f);
  float var = ss * (1.0f / 512.0f) - mean * mean;
  float inv = rsqrtf(var + 1e-5f);
  u16x8 o8;
#pragma unroll
  for (int j = 0; j < 8; ++j) o8[j] = f2b((vv[j] - mean) * inv * g[c + j] + bb[c + j]);
  *(u16x8*)(a1 + (size_t)row * 512 + c) = o8;
}

// ---------------- LayerNorm (D=512 -> bf16 out), one wave per row; INBF: input dtype ----
template<int INBF>
__global__ __launch_bounds__(256) void ln_rows(const void* __restrict__ in,
    const float* __restrict__ g, const float* __restrict__ b,
    unsigned short* __restrict__ out, int M) {
  int row = blockIdx.x * 4 + (threadIdx.x >> 6);
  int lane = threadIdx.x & 63;
  float vv[8];
  if (INBF) {
    u16x8 v8 = *(const u16x8*)((const unsigned short*)in + (size_t)row * 512 + lane * 8);
#pragma unroll
    for (int j = 0; j < 8; ++j) vv[j] = b2f(v8[j]);
  } else {
    const float* rp = (const float*)in + (size_t)row * 512;
    float4 v0 = ((const float4*)rp)[lane * 2];
    float4 v1 = ((const float4*)rp)[lane * 2 + 1];
    vv[0] = v0.x; vv[1] = v0.y; vv[2] = v0.z; vv[3] = v0.w;
    vv[4] = v1.x; vv[5] = v1.y; vv[6] = v1.z; vv[7] = v1.w;
  }
  float s = 0.f, ss = 0.f;
#pragma unroll
  for (int j = 0; j < 8; ++j) { s += vv[j]; ss += vv[j] * vv[j]; }
#pragma unroll
  for (int o = 1; o < 64; o <<= 1) { s += __shfl_xor(s, o); ss += __shfl_xor(ss, o); }
  float mean = s * (1.0f / 512.0f);
  float var = ss * (1.0f / 512.0f) - mean * mean;
  float inv = rsqrtf(var + 1e-5f);
  int c = lane * 8;
  u16x8 o8;
#pragma unroll
  for (int j = 0; j < 8; ++j) o8[j] = f2b((vv[j] - mean) * inv * g[c + j] + b[c + j]);
  *(u16x8*)(out + (size_t)row * 512 + c) = o8;
}

// ---------------- FUSED mean over WS=3 + LNq (wave per position) ----------------
__global__ __launch_bounds__(256) void mean3_lnq(const unsigned short* __restrict__ x,
    const float* __restrict__ g, const float* __restrict__ bb,
    float* __restrict__ enc, unsigned short* __restrict__ lnq) {
  int p = blockIdx.x * 4 + (threadIdx.x >> 6);   // 0..4095
  int lane = threadIdx.x & 63;
  int c = lane * 8;
  u16x8 a = *(const u16x8*)(x + ((size_t)(p * 3 + 0) * 512 + c));
  u16x8 b = *(const u16x8*)(x + ((size_t)(p * 3 + 1) * 512 + c));
  u16x8 d = *(const u16x8*)(x + ((size_t)(p * 3 + 2) * 512 + c));
  float vv[8];
#pragma unroll
  for (int j = 0; j < 8; ++j) vv[j] = (b2f(a[j]) + b2f(b[j]) + b2f(d[j])) * (1.0f / 3.0f);
  float4 e0, e1;
  e0.x = vv[0]; e0.y = vv[1]; e0.z = vv[2]; e0.w = vv[3];
  e1.x = vv[4]; e1.y = vv[5]; e1.z = vv[6]; e1.w = vv[7];
  float* ep = enc + (size_t)p * 512 + c;
  ((float4*)ep)[0] = e0; ((float4*)ep)[1] = e1;
  float s = 0.f, ss = 0.f;
#pragma unroll
  for (int j = 0; j < 8; ++j) { s += vv[j]; ss += vv[j] * vv[j]; }
#pragma unroll
  for (int o = 1; o < 64; o <<= 1) { s += __shfl_xor(s, o); ss += __shfl_xor(ss, o); }
  float mean = s * (1.0f / 512.0f);
  float var = ss * (1.0f / 512.0f) - mean * mean;
  float inv = rsqrtf(var + 1e-5f);
  u16x8 o8;
#pragma unroll
  for (int j = 0; j < 8; ++j) o8[j] = f2b((vv[j] - mean) * inv * g[c + j] + bb[c + j]);
  *(u16x8*)(lnq + (size_t)p * 512 + c) = o8;
}

// ======== shared epilogue (wide stores; swapped-operand C layout) ========
template<int RES, int GELU, int OUTBF, int KVT>
__device__ __forceinline__ void epi_store(f32x4 v, int row, int col,
    const float* __restrict__ bias, const void* __restrict__ res,
    void* __restrict__ outp, int N) {
  f32x4 b4 = *(const f32x4*)(bias + col);
  v += b4;
  if (GELU) {
#pragma unroll
    for (int r = 0; r < 4; ++r)
      v[r] = 0.5f * v[r] * (1.0f + erff(v[r] * 0.70710678118654752f));
  }
  if (RES == 1) v += *(const f32x4*)((const float*)res + (size_t)row * N + col);
  if (RES == 2) {
    u16x4 r4 = *(const u16x4*)((const unsigned short*)res + (size_t)row * N + col);
#pragma unroll
    for (int r = 0; r < 4; ++r) v[r] += b2f(r4[r]);
  }
  if (KVT) {
    // row = b*1024 + n_vis ; col<512 -> K head block (contig dd), col>=512 -> V^T
    int bb = row >> 10, nn = row & 1023;
    unsigned short* Kp = (unsigned short*)outp;
    unsigned short* VpT = Kp + 16777216u;
    if (col < 512) {
      int hh = col >> 5, dd = col & 31;
      u16x4 o4;
#pragma unroll
      for (int r = 0; r < 4; ++r) o4[r] = f2b(v[r]);
      *(u16x4*)(Kp + (((size_t)(bb * 16 + hh)) * 1024 + nn) * 32 + dd) = o4;
    } else {
      int cc = col - 512, hh = cc >> 5, dd = cc & 31;
#pragma unroll
      for (int r = 0; r < 4; ++r)
        VpT[(((size_t)(bb * 16 + hh)) * 32 + dd + r) * 1024 + nn] = f2b(v[r]);
    }
  } else if (OUTBF) {
    u16x4 o4;
#pragma unroll
    for (int r = 0; r < 4; ++r) o4[r] = f2b(v[r]);
    *(u16x4*)((unsigned short*)outp + (size_t)row * N + col) = o4;
  } else {
    *(f32x4*)((float*)outp + (size_t)row * N + col) = v;
  }
}

// ---------------- bf16 MFMA GEMM, 128x128, BK=32, 3-slot ring (round-12, proven) -------
// Prefetch-distance-2: loads for step t issued at t-2; one raw s_barrier/step; counted
// vmcnt(4) (never 0 in steady state); trailing lgkmcnt(0) fences slot reuse.
// __launch_bounds__(256,3): 144 total regs/thread (80 arch + 64 acc) fits 3 waves/SIMD
// -> request 3 blocks/CU residency (was 2; LDS 3x48KB=144<=160KB fits).
// Row-pair XOR swizzle (bank-conflict-free, measured 0); swapped-operand MFMA ->
// wide epilogue stores; col-fastest block order; bijective XCD swizzle.
template<int RES, int GELU, int OUTBF, int KVT>
__global__ __launch_bounds__(256, 3) void gemm128(
    const unsigned short* __restrict__ A, const unsigned short* __restrict__ Bt,
    const float* __restrict__ bias, const void* __restrict__ res,
    void* __restrict__ outp, int M, int N, int K) {
  __shared__ unsigned short sA[3][4096];
  __shared__ unsigned short sB[3][4096];
  const int tid = threadIdx.x;
  const int nbx = gridDim.x;
  int id = blockIdx.y * nbx + blockIdx.x;
  {
    const int nwg = nbx * gridDim.y;
    if ((nwg & 7) == 0) id = (id & 7) * (nwg >> 3) + (id >> 3);
  }
  const int bm = (id / nbx) * 128, bn = (id % nbx) * 128;   // col-fastest (proven)
  const int wave = tid >> 6, lane = tid & 63;
  const int wr = (wave >> 1) * 64, wc = (wave & 1) * 64;
  const int lrow = lane & 15, g = lane >> 4;
  f32x4 acc[4][4] = {};
  const int xoff = (((((lrow & 1) << 2) | g) ^ ((lrow >> 1) & 7)) << 3);
  const int baseA = ((wr >> 1) + (lrow >> 1)) * 64 + xoff;
  const int baseB = ((wc >> 1) + (lrow >> 1)) * 64 + xoff;
  const int slot8 = (tid & 7) ^ ((tid >> 3) & 7);
  const int srow = ((tid >> 3) << 1) + (slot8 >> 2);
  const int scol = (slot8 & 3) << 3;
  const unsigned short* gA = A + (size_t)(bm + srow) * K + scol;
  const unsigned short* gB = Bt + (size_t)(bn + srow) * K + scol;
  const int NT = K >> 5;

#define STG(slot, kt)                                                          \
  { _Pragma("unroll")                                                          \
    for (int i = 0; i < 2; ++i) {                                              \
      GLOAD16(gA + (size_t)(i * 64) * K + (kt) * 32, &sA[slot][i * 2048 + wave * 512]); \
      GLOAD16(gB + (size_t)(i * 64) * K + (kt) * 32, &sB[slot][i * 2048 + wave * 512]); \
    } }

  STG(0, 0);
  STG(1, 1);
  int sl = 0;
  for (int t = 0; t < NT; ++t) {
    if (t < NT - 1) asm volatile("s_waitcnt vmcnt(4)" ::: "memory");
    else            asm volatile("s_waitcnt vmcnt(0)" ::: "memory");
    __builtin_amdgcn_s_barrier();
    __builtin_amdgcn_sched_barrier(0);
    if (t + 2 < NT) {
      int sl2 = sl - 1; if (sl2 < 0) sl2 = 2;
      STG(sl2, t + 2);
    }
    s16x8 av[4], bv[4];
#pragma unroll
    for (int m = 0; m < 4; ++m) av[m] = *(const s16x8*)&sA[sl][baseA + m * 512];
#pragma unroll
    for (int n = 0; n < 4; ++n) bv[n] = *(const s16x8*)&sB[sl][baseB + n * 512];
    __builtin_amdgcn_s_setprio(1);
#pragma unroll
    for (int m = 0; m < 4; ++m)
#pragma unroll
      for (int n = 0; n < 4; ++n)
        acc[m][n] = __builtin_amdgcn_mfma_f32_16x16x32_bf16(bv[n], av[m], acc[m][n], 0, 0, 0);
    __builtin_amdgcn_s_setprio(0);
    asm volatile("s_waitcnt lgkmcnt(0)" ::: "memory");
    sl = (sl == 2) ? 0 : sl + 1;
  }
#undef STG

  const int orow_ = bm + wr + lrow;
  const int ocol_ = bn + wc + g * 4;
#pragma unroll
  for (int m = 0; m < 4; ++m)
#pragma unroll
    for (int n = 0; n < 4; ++n)
      epi_store<RES, GELU, OUTBF, KVT>(acc[m][n], orow_ + m * 16, ocol_ + n * 16,
                                       bias, res, outp, N);
}

// ---------------- windowed (WS=3) attention, thread per (side-pos, head, q-row) ----------------
__global__ __launch_bounds__(256) void winattn(const unsigned short* __restrict__ qkv,
                                               unsigned short* __restrict__ o) {
  int g = blockIdx.x * 256 + threadIdx.x;
  if (g >= 4096 * 48) return;
  int i = g % 3;
  int t = g / 3;
  int h = t & 15;
  int sp = t >> 4;
  const unsigned short* base = qkv + (size_t)sp * 4608 + h * 32;
  float qv[32];
  {
    const u16x8* qp = (const u16x8*)(base + (size_t)i * 1536);
#pragma unroll
    for (int c = 0; c < 4; ++c) {
      u16x8 v = qp[c];
#pragma unroll
      for (int j = 0; j < 8; ++j) qv[c * 8 + j] = b2f(v[j]);
    }
  }
  float s[3];
#pragma unroll
  for (int j3 = 0; j3 < 3; ++j3) {
    const u16x8* kp = (const u16x8*)(base + (size_t)j3 * 1536 + 512);
    float acc = 0.f;
#pragma unroll
    for (int c = 0; c < 4; ++c) {
      u16x8 v = kp[c];
#pragma unroll
      for (int j = 0; j < 8; ++j) acc += qv[c * 8 + j] * b2f(v[j]);
    }
    s[j3] = acc * 0.17677669529663687f;
  }
  float mx = fmaxf(s[0], fmaxf(s[1], s[2]));
  float e0 = __expf(s[0] - mx), e1 = __expf(s[1] - mx), e2 = __expf(s[2] - mx);
  float inv = 1.0f / (e0 + e1 + e2);
  float a0 = e0 * inv, a1 = e1 * inv, a2 = e2 * inv;
  unsigned short* op = o + (size_t)(sp * 3 + i) * 512 + h * 32;
  const u16x8* v0p = (const u16x8*)(base + 1024);
  const u16x8* v1p = (const u16x8*)(base + 1536 + 1024);
  const u16x8* v2p = (const u16x8*)(base + 3072 + 1024);
#pragma unroll
  for (int c = 0; c < 4; ++c) {
    u16x8 x0 = v0p[c], x1 = v1p[c], x2 = v2p[c];
    u16x8 ov;
#pragma unroll
    for (int j = 0; j < 8; ++j)
      ov[j] = f2b(a0 * b2f(x0[j]) + a1 * b2f(x1[j]) + a2 * b2f(x2[j]));
    *(u16x8*)(op + c * 8) = ov;
  }
}

// ---------------- cross attention, MFMA flash style; BOTH sides per (b,h) block ----------------
__global__ __launch_bounds__(512) void crossattn_mfma(const unsigned short* __restrict__ q,
    const unsigned short* __restrict__ Kp, const unsigned short* __restrict__ VpT,
    unsigned short* __restrict__ o) {
  __shared__ unsigned short Plds[8][2][16 * 40];
  const int bh = blockIdx.x;
  const int b = bh >> 4, h = bh & 15;
  const int tid = threadIdx.x;
  const int w = tid >> 6, lane = tid & 63;
  const int side = w >> 2, wsub = w & 3;
  const int ql = lane & 15, g = lane >> 4;
  const int qrow = side * 2048 + b * 64 + wsub * 16 + ql;
  const float SC = 0.17677669529663687f;
  s16x8 qf;
  {
    u16x8 qv8 = *(const u16x8*)(q + (size_t)qrow * 512 + h * 32 + g * 8);
#pragma unroll
    for (int j = 0; j < 8; ++j) qf[j] = (short)f2b(b2f(qv8[j]) * SC);
  }
  const unsigned short* kbase = Kp + ((size_t)(b * 16 + h) * 1024) * 32;
  const unsigned short* vbase = VpT + ((size_t)(b * 16 + h) * 32) * 1024;
  f32x4 oacc0 = {}, oacc1 = {};
  float m_run = -1e30f, l_part = 0.f;
  for (int kv0 = 0; kv0 < 1024; kv0 += 32) {
    const int pp = (kv0 >> 5) & 1;
    s16x8 kf0 = *(const s16x8*)(kbase + (size_t)(kv0 + ql) * 32 + g * 8);
    s16x8 kf1 = *(const s16x8*)(kbase + (size_t)(kv0 + 16 + ql) * 32 + g * 8);
    f32x4 z = {0.f, 0.f, 0.f, 0.f};
    f32x4 s0 = __builtin_amdgcn_mfma_f32_16x16x32_bf16(kf0, qf, z, 0, 0, 0);
    f32x4 s1 = __builtin_amdgcn_mfma_f32_16x16x32_bf16(kf1, qf, z, 0, 0, 0);
    float cm = fmaxf(fmaxf(fmaxf(s0[0], s0[1]), fmaxf(s0[2], s0[3])),
                     fmaxf(fmaxf(s1[0], s1[1]), fmaxf(s1[2], s1[3])));
    cm = fmaxf(cm, __shfl_xor(cm, 16));
    cm = fmaxf(cm, __shfl_xor(cm, 32));
    float m_new = fmaxf(m_run, cm);
    float corr = __expf(m_run - m_new);
    m_run = m_new;
    float p0[4], p1[4], ps = 0.f;
#pragma unroll
    for (int r = 0; r < 4; ++r) {
      p0[r] = __expf(s0[r] - m_new);
      p1[r] = __expf(s1[r] - m_new);
      ps += p0[r] + p1[r];
    }
    l_part = l_part * corr + ps;
    oacc0 *= corr; oacc1 *= corr;
    u16x4 w0, w1;
#pragma unroll
    for (int r = 0; r < 4; ++r) { w0[r] = f2b(p0[r]); w1[r] = f2b(p1[r]); }
    *(u16x4*)&Plds[w][pp][ql * 40 + g * 4] = w0;
    *(u16x4*)&Plds[w][pp][ql * 40 + 16 + g * 4] = w1;
    __syncthreads();
    s16x8 pf = *(const s16x8*)&Plds[w][pp][ql * 40 + g * 8];
    s16x8 vf0 = *(const s16x8*)(vbase + (size_t)ql * 1024 + kv0 + g * 8);
    s16x8 vf1 = *(const s16x8*)(vbase + (size_t)(16 + ql) * 1024 + kv0 + g * 8);
    oacc0 = __builtin_amdgcn_mfma_f32_16x16x32_bf16(vf0, pf, oacc0, 0, 0, 0);
    oacc1 = __builtin_amdgcn_mfma_f32_16x16x32_bf16(vf1, pf, oacc1, 0, 0, 0);
  }
  float lf = l_part;
  lf += __shfl_xor(lf, 16);
  lf += __shfl_xor(lf, 32);
  float inv = 1.0f / lf;
  unsigned short* op = o + (size_t)qrow * 512 + h * 32;
  u16x4 ov0, ov1;
#pragma unroll
  for (int r = 0; r < 4; ++r) {
    ov0[r] = f2b(oacc0[r] * inv);
    ov1[r] = f2b(oacc1[r] * inv);
  }
  *(u16x4*)(op + g * 4) = ov0;
  *(u16x4*)(op + 16 + g * 4) = ov1;
}

// ---------------- targets pass-through (output 2) ----------------
__global__ void tail_targets(const int* __restrict__ t, float* __restrict__ out) {
  int i = blockIdx.x * 256 + threadIdx.x;
  if (i < 2048) out[33554432 + i] = (float)t[i];
}

extern "C" void kernel_launch(void* const* d_in, const int* in_sizes, int n_in,
                              void* d_out, int out_size, void* d_ws, size_t ws_size,
                              hipStream_t stream) {
  const float* visual   = (const float*)d_in[0];
  const int*   targets  = (const int*)d_in[1];
  const int*   pad_p    = (const int*)d_in[2];
  const float* char_emb = (const float*)d_in[3];
  const float* ln1_g = (const float*)d_in[4];
  const float* ln1_b = (const float*)d_in[5];
  const float* in_proj_w = (const float*)d_in[6];
  const float* in_proj_b = (const float*)d_in[7];
  const float* out_w = (const float*)d_in[8];
  const float* out_b = (const float*)d_in[9];
  const float* fc1_w = (const float*)d_in[10];
  const float* fc1_b = (const float*)d_in[11];
  const float* fc2_w = (const float*)d_in[12];
  const float* fc2_b = (const float*)d_in[13];
  const float* ln2_g = (const float*)d_in[14];
  const float* ln2_b = (const float*)d_in[15];
  const float* ltok  = (const float*)d_in[16];
  const float* rtok  = (const float*)d_in[17];
  const float* q_w   = (const float*)d_in[18];
  const float* q_b   = (const float*)d_in[19];
  const float* kv_w  = (const float*)d_in[20];
  const float* kv_b  = (const float*)d_in[21];
  const float* proj_w = (const float*)d_in[22];
  const float* proj_b = (const float*)d_in[23];
  const float* lnq_g = (const float*)d_in[24];
  const float* lnq_b = (const float*)d_in[25];
  const float* lnkv_g = (const float*)d_in[26];
  const float* lnkv_b = (const float*)d_in[27];
  const float* head_w = (const float*)d_in[28];
  const float* head_b = (const float*)d_in[29];

  // workspace layout (bytes); Kp+VpT (bf16, 67MB) alias the dead encoder region
  char* ws = (char*)d_ws;
  unsigned short* W    = (unsigned short*)ws;                    // 14,680,064 B weights bf16
  unsigned short* XB   = (unsigned short*)(ws + 14680064ull);    // 12,582,912 B x bf16 12288x512
  unsigned short* KP   = (unsigned short*)(ws + 14680064ull);    // alias: 33,554,432 B Kp + 33,554,432 B VpT
  unsigned short* A1   = (unsigned short*)(ws + 39845888ull);    // 12,582,912 B bf16 12288x512
  unsigned short* B1   = (unsigned short*)(ws + 52428800ull);    // 25,165,824 B bf16 12288x1024
  unsigned short* QKV  = (unsigned short*)(ws + 77594624ull);    // 37,748,736 B bf16 12288x1536
  float*          ENC  = (float*)(ws + 115343360ull);            //  8,388,608 B fp32 4096x512
  unsigned short* VIS  = (unsigned short*)(ws + 123731968ull);   // 33,554,432 B bf16 32768x512
  unsigned short* Q    = (unsigned short*)(ws + 157286400ull);   //  4,194,304 B bf16 4096x512
  unsigned short* OC   = (unsigned short*)(ws + 165675008ull);   //  4,194,304 B bf16 4096x512
  unsigned short* FEAT = (unsigned short*)(ws + 169869312ull);   //  4,194,304 B bf16 4096x512
  unsigned short* LNQ  = (unsigned short*)(ws + 174063616ull);   //  4,194,304 B bf16 4096x512
  unsigned short* VPT  = KP + 16777216u;

  unsigned short* Wip   = W;
  unsigned short* Wout  = W + 786432;
  unsigned short* Wfc1  = W + 1048576;
  unsigned short* Wfc2  = W + 1572864;
  unsigned short* Wq    = W + 2097152;
  unsigned short* Wkv   = W + 2359296;
  unsigned short* Wproj = W + 2883584;
  unsigned short* Whead = W + 3145728;

  // one fused convert for all 8 weight matrices (1,835,008 float4 chunks)
  cvt_all<<<dim3(7168), dim3(256), 0, stream>>>(in_proj_w, out_w, fc1_w, fc2_w,
                                                q_w, kv_w, proj_w, head_w, W);

  // ---- encoders (left+right batched, M=12288) ----
  embed_ln1<<<dim3(3072), dim3(256), 0, stream>>>(targets, pad_p, char_emb, ltok, rtok,
                                                  ln1_g, ln1_b, XB, A1);
  gemm128<0,0,1,0><<<dim3(12, 96), dim3(256), 0, stream>>>(A1, Wip, in_proj_b, nullptr, QKV, 12288, 1536, 512);
  winattn<<<dim3(768), dim3(256), 0, stream>>>(QKV, B1);
  gemm128<2,0,1,0><<<dim3(4, 96), dim3(256), 0, stream>>>(B1, Wout, out_b, XB, XB, 12288, 512, 512);
  ln_rows<1><<<dim3(3072), dim3(256), 0, stream>>>(XB, ln2_g, ln2_b, A1, 12288);
  gemm128<0,1,1,0><<<dim3(8, 96), dim3(256), 0, stream>>>(A1, Wfc1, fc1_b, nullptr, B1, 12288, 1024, 512);
  gemm128<2,0,1,0><<<dim3(4, 96), dim3(256), 0, stream>>>(B1, Wfc2, fc2_b, XB, XB, 12288, 512, 1024);
  mean3_lnq<<<dim3(1024), dim3(256), 0, stream>>>(XB, lnq_g, lnq_b, ENC, LNQ);

  // ---- cross attention (kv shared by both sides; encoder buffers now dead) ----
  ln_rows<0><<<dim3(8192), dim3(256), 0, stream>>>(visual, lnkv_g, lnkv_b, VIS, 32768);
  gemm128<0,0,1,1><<<dim3(8, 256), dim3(256), 0, stream>>>(VIS, Wkv, kv_b, nullptr, KP, 32768, 1024, 512);
  gemm128<0,0,1,0><<<dim3(4, 32), dim3(256), 0, stream>>>(LNQ, Wq, q_b, nullptr, Q, 4096, 512, 512);
  crossattn_mfma<<<dim3(512), dim3(512), 0, stream>>>(Q, KP, VPT, OC);
  gemm128<1,0,1,0><<<dim3(4, 32), dim3(256), 0, stream>>>(OC, Wproj, proj_b, ENC, FEAT, 4096, 512, 512);

  // ---- head -> d_out (rows 0..2047 = sgm_left, 2048..4095 = sgm_right) ----
  gemm128<0,0,0,0><<<dim3(64, 32), dim3(256), 0, stream>>>(FEAT, Whead, head_b, nullptr, (float*)d_out, 4096, 8192, 512);
  tail_targets<<<dim3(8), dim3(256), 0, stream>>>(targets, (float*)d_out);
}

// Round 18
// 378.591 us; speedup vs baseline: 1.0602x; 1.0052x over previous
//
#include <hip/hip_runtime.h>
#include <hip/hip_bf16.h>
#include <cstdint>
#include <cstddef>

// SGM fused pipeline, MI355X gfx950.  (Round-17 best config, consolidated.)
// Shapes: B=32 L=64 N=1024 D=512 C=8192 WS=3 NH=16 HD=32 HID=1024
// Encoder rows M=12288 (side*6144 + pos*3 + w), cross rows 4096 (side*2048+pos).
// Residual stream X and Q are bf16 (threshold headroom ~20000x).
// GEMM: gemm128 ring-3 counted-vmcnt, col-fastest+XCD swizzle, launch_bounds(256,3)
// (3 blocks/CU: VGPR 144/thread and LDS 3x48KB both exactly fit).

typedef __attribute__((ext_vector_type(8))) short s16x8;
typedef __attribute__((ext_vector_type(8))) unsigned short u16x8;
typedef __attribute__((ext_vector_type(4))) unsigned short u16x4;
typedef __attribute__((ext_vector_type(4))) float f32x4;

__device__ __forceinline__ float b2f(unsigned short u) {
  union { unsigned int i; float f; } c; c.i = ((unsigned int)u) << 16; return c.f;
}
__device__ __forceinline__ unsigned short f2b(float f) {
  union { float f; unsigned int i; } c; c.f = f;
  unsigned int x = c.i;
  return (unsigned short)((x + 0x7FFFu + ((x >> 16) & 1u)) >> 16); // RNE, no NaN in this net
}

// async global->LDS, 16B per lane; LDS dest is wave-uniform base + lane*16
#define GLOAD16(gp, lp)                                                        \
  __builtin_amdgcn_global_load_lds(                                           \
      (const __attribute__((address_space(1))) void*)(gp),                    \
      (__attribute__((address_space(3))) void*)(lp), 16, 0, 0)

// ---------------- fused fp32 -> bf16 convert for ALL weights (1 launch) ----------------
__global__ void cvt_all(const float* __restrict__ s0, const float* __restrict__ s1,
                        const float* __restrict__ s2, const float* __restrict__ s3,
                        const float* __restrict__ s4, const float* __restrict__ s5,
                        const float* __restrict__ s6, const float* __restrict__ s7,
                        unsigned short* __restrict__ d) {
  int c = blockIdx.x * 256 + threadIdx.x;
  if (c >= 1835008) return;
  int e = c * 4;
  const float* sp; int off;
  if      (e <  786432) { sp = s0; off = 0; }
  else if (e < 1048576) { sp = s1; off =  786432; }
  else if (e < 1572864) { sp = s2; off = 1048576; }
  else if (e < 2097152) { sp = s3; off = 1572864; }
  else if (e < 2359296) { sp = s4; off = 2097152; }
  else if (e < 2883584) { sp = s5; off = 2359296; }
  else if (e < 3145728) { sp = s6; off = 2883584; }
  else                  { sp = s7; off = 3145728; }
  float4 v = *(const float4*)(sp + (e - off));
  u16x4 o; o[0] = f2b(v.x); o[1] = f2b(v.y); o[2] = f2b(v.z); o[3] = f2b(v.w);
  *(u16x4*)(d + e) = o;
}

// ---------------- FUSED embed + token + LN1 (wave per row; id is row-uniform) -----------
__global__ __launch_bounds__(256) void embed_ln1(const int* __restrict__ targets,
    const int* __restrict__ pad_p, const float* __restrict__ ce,
    const float* __restrict__ ltok, const float* __restrict__ rtok,
    const float* __restrict__ g, const float* __restrict__ bb,
    unsigned short* __restrict__ xb, unsigned short* __restrict__ a1) {
  int row = blockIdx.x * 4 + (threadIdx.x >> 6);   // 0..12287
  int lane = threadIdx.x & 63;
  int side = row >= 6144;
  int rem = row - side * 6144;
  int pos = rem / 3, w = rem - pos * 3;
  int b = pos >> 6, l = pos & 63;
  int id;
  if (!side) { int ti = l + w - 3; id = (ti >= 0) ? targets[(b << 6) + ti] : *pad_p; }
  else       { int ti = l + w + 1; id = (ti < 64) ? targets[(b << 6) + ti] : *pad_p; }
  const float* cp = ce + (size_t)id * 512 + lane * 8;
  const float* tp = (side ? rtok : ltok) + lane * 8;
  float4 c0 = ((const float4*)cp)[0], c1 = ((const float4*)cp)[1];
  float4 t0 = ((const float4*)tp)[0], t1 = ((const float4*)tp)[1];
  float vv[8] = {c0.x + t0.x, c0.y + t0.y, c0.z + t0.z, c0.w + t0.w,
                 c1.x + t1.x, c1.y + t1.y, c1.z + t1.z, c1.w + t1.w};
  int c = lane * 8;
  u16x8 xo;
#pragma unroll
  for (int j = 0; j < 8; ++j) xo[j] = f2b(vv[j]);
  *(u16x8*)(xb + (size_t)row * 512 + c) = xo;
  float s = 0.f, ss = 0.f;
#pragma unroll
  for (int j = 0; j < 8; ++j) { s += vv[j]; ss += vv[j] * vv[j]; }
#pragma unroll
  for (int o = 1; o < 64; o <<= 1) { s += __shfl_xor(s, o); ss += __shfl_xor(ss, o); }
  float mean = s * (1.0f / 512.0f);
  float var = ss * (1.0f / 512.0f) - mean * mean;
  float inv = rsqrtf(var + 1e-5f);
  u16x8 o8;
#pragma unroll
  for (int j = 0; j < 8; ++j) o8[j] = f2b((vv[j] - mean) * inv * g[c + j] + bb[c + j]);
  *(u16x8*)(a1 + (size_t)row * 512 + c) = o8;
}

// ---------------- LayerNorm (D=512 -> bf16 out), one wave per row; INBF: input dtype ----
template<int INBF>
__global__ __launch_bounds__(256) void ln_rows(const void* __restrict__ in,
    const float* __restrict__ g, const float* __restrict__ b,
    unsigned short* __restrict__ out, int M) {
  int row = blockIdx.x * 4 + (threadIdx.x >> 6);
  int lane = threadIdx.x & 63;
  float vv[8];
  if (INBF) {
    u16x8 v8 = *(const u16x8*)((const unsigned short*)in + (size_t)row * 512 + lane * 8);
#pragma unroll
    for (int j = 0; j < 8; ++j) vv[j] = b2f(v8[j]);
  } else {
    const float* rp = (const float*)in + (size_t)row * 512;
    float4 v0 = ((const float4*)rp)[lane * 2];
    float4 v1 = ((const float4*)rp)[lane * 2 + 1];
    vv[0] = v0.x; vv[1] = v0.y; vv[2] = v0.z; vv[3] = v0.w;
    vv[4] = v1.x; vv[5] = v1.y; vv[6] = v1.z; vv[7] = v1.w;
  }
  float s = 0.f, ss = 0.f;
#pragma unroll
  for (int j = 0; j < 8; ++j) { s += vv[j]; ss += vv[j] * vv[j]; }
#pragma unroll
  for (int o = 1; o < 64; o <<= 1) { s += __shfl_xor(s, o); ss += __shfl_xor(ss, o); }
  float mean = s * (1.0f / 512.0f);
  float var = ss * (1.0f / 512.0f) - mean * mean;
  float inv = rsqrtf(var + 1e-5f);
  int c = lane * 8;
  u16x8 o8;
#pragma unroll
  for (int j = 0; j < 8; ++j) o8[j] = f2b((vv[j] - mean) * inv * g[c + j] + b[c + j]);
  *(u16x8*)(out + (size_t)row * 512 + c) = o8;
}

// ---------------- FUSED mean over WS=3 + LNq (+ targets pass-through) ----------------
__global__ __launch_bounds__(256) void mean3_lnq(const unsigned short* __restrict__ x,
    const float* __restrict__ g, const float* __restrict__ bb,
    float* __restrict__ enc, unsigned short* __restrict__ lnq,
    const int* __restrict__ targets, float* __restrict__ out2) {
  // fold output-2 (targets as float) into this launch: flat ids 0..2047
  int fid = blockIdx.x * 256 + threadIdx.x;
  if (fid < 2048) out2[fid] = (float)targets[fid];
  int p = blockIdx.x * 4 + (threadIdx.x >> 6);   // 0..4095
  int lane = threadIdx.x & 63;
  int c = lane * 8;
  u16x8 a = *(const u16x8*)(x + ((size_t)(p * 3 + 0) * 512 + c));
  u16x8 b = *(const u16x8*)(x + ((size_t)(p * 3 + 1) * 512 + c));
  u16x8 d = *(const u16x8*)(x + ((size_t)(p * 3 + 2) * 512 + c));
  float vv[8];
#pragma unroll
  for (int j = 0; j < 8; ++j) vv[j] = (b2f(a[j]) + b2f(b[j]) + b2f(d[j])) * (1.0f / 3.0f);
  float4 e0, e1;
  e0.x = vv[0]; e0.y = vv[1]; e0.z = vv[2]; e0.w = vv[3];
  e1.x = vv[4]; e1.y = vv[5]; e1.z = vv[6]; e1.w = vv[7];
  float* ep = enc + (size_t)p * 512 + c;
  ((float4*)ep)[0] = e0; ((float4*)ep)[1] = e1;
  float s = 0.f, ss = 0.f;
#pragma unroll
  for (int j = 0; j < 8; ++j) { s += vv[j]; ss += vv[j] * vv[j]; }
#pragma unroll
  for (int o = 1; o < 64; o <<= 1) { s += __shfl_xor(s, o); ss += __shfl_xor(ss, o); }
  float mean = s * (1.0f / 512.0f);
  float var = ss * (1.0f / 512.0f) - mean * mean;
  float inv = rsqrtf(var + 1e-5f);
  u16x8 o8;
#pragma unroll
  for (int j = 0; j < 8; ++j) o8[j] = f2b((vv[j] - mean) * inv * g[c + j] + bb[c + j]);
  *(u16x8*)(lnq + (size_t)p * 512 + c) = o8;
}

// ======== shared epilogue (wide stores; swapped-operand C layout) ========
template<int RES, int GELU, int OUTBF, int KVT>
__device__ __forceinline__ void epi_store(f32x4 v, int row, int col,
    const float* __restrict__ bias, const void* __restrict__ res,
    void* __restrict__ outp, int N) {
  f32x4 b4 = *(const f32x4*)(bias + col);
  v += b4;
  if (GELU) {
#pragma unroll
    for (int r = 0; r < 4; ++r)
      v[r] = 0.5f * v[r] * (1.0f + erff(v[r] * 0.70710678118654752f));
  }
  if (RES == 1) v += *(const f32x4*)((const float*)res + (size_t)row * N + col);
  if (RES == 2) {
    u16x4 r4 = *(const u16x4*)((const unsigned short*)res + (size_t)row * N + col);
#pragma unroll
    for (int r = 0; r < 4; ++r) v[r] += b2f(r4[r]);
  }
  if (KVT) {
    // row = b*1024 + n_vis ; col<512 -> K head block (contig dd), col>=512 -> V^T
    int bb = row >> 10, nn = row & 1023;
    unsigned short* Kp = (unsigned short*)outp;
    unsigned short* VpT = Kp + 16777216u;
    if (col < 512) {
      int hh = col >> 5, dd = col & 31;
      u16x4 o4;
#pragma unroll
      for (int r = 0; r < 4; ++r) o4[r] = f2b(v[r]);
      *(u16x4*)(Kp + (((size_t)(bb * 16 + hh)) * 1024 + nn) * 32 + dd) = o4;
    } else {
      int cc = col - 512, hh = cc >> 5, dd = cc & 31;
#pragma unroll
      for (int r = 0; r < 4; ++r)
        VpT[(((size_t)(bb * 16 + hh)) * 32 + dd + r) * 1024 + nn] = f2b(v[r]);
    }
  } else if (OUTBF) {
    u16x4 o4;
#pragma unroll
    for (int r = 0; r < 4; ++r) o4[r] = f2b(v[r]);
    *(u16x4*)((unsigned short*)outp + (size_t)row * N + col) = o4;
  } else {
    *(f32x4*)((float*)outp + (size_t)row * N + col) = v;
  }
}

// ---------------- bf16 MFMA GEMM, 128x128, BK=32, 3-slot ring, 3 blocks/CU -------
// Prefetch-distance-2: loads for step t issued at t-2; one raw s_barrier/step; counted
// vmcnt(4) (never 0 in steady state); trailing lgkmcnt(0) fences slot reuse.
// __launch_bounds__(256,3): 144 total regs/thread (80 arch + 64 acc) = 3 waves/SIMD;
// LDS 3x48KB = 144KB fits 3 blocks/CU (round-17: 395->380us, the occupancy lever).
// Row-pair XOR swizzle (bank-conflict-free, measured 0); swapped-operand MFMA ->
// wide epilogue stores; col-fastest block order; bijective XCD swizzle.
template<int RES, int GELU, int OUTBF, int KVT>
__global__ __launch_bounds__(256, 3) void gemm128(
    const unsigned short* __restrict__ A, const unsigned short* __restrict__ Bt,
    const float* __restrict__ bias, const void* __restrict__ res,
    void* __restrict__ outp, int M, int N, int K) {
  __shared__ unsigned short sA[3][4096];
  __shared__ unsigned short sB[3][4096];
  const int tid = threadIdx.x;
  const int nbx = gridDim.x;
  int id = blockIdx.y * nbx + blockIdx.x;
  {
    const int nwg = nbx * gridDim.y;
    if ((nwg & 7) == 0) id = (id & 7) * (nwg >> 3) + (id >> 3);
  }
  const int bm = (id / nbx) * 128, bn = (id % nbx) * 128;   // col-fastest (proven)
  const int wave = tid >> 6, lane = tid & 63;
  const int wr = (wave >> 1) * 64, wc = (wave & 1) * 64;
  const int lrow = lane & 15, g = lane >> 4;
  f32x4 acc[4][4] = {};
  const int xoff = (((((lrow & 1) << 2) | g) ^ ((lrow >> 1) & 7)) << 3);
  const int baseA = ((wr >> 1) + (lrow >> 1)) * 64 + xoff;
  const int baseB = ((wc >> 1) + (lrow >> 1)) * 64 + xoff;
  const int slot8 = (tid & 7) ^ ((tid >> 3) & 7);
  const int srow = ((tid >> 3) << 1) + (slot8 >> 2);
  const int scol = (slot8 & 3) << 3;
  const unsigned short* gA = A + (size_t)(bm + srow) * K + scol;
  const unsigned short* gB = Bt + (size_t)(bn + srow) * K + scol;
  const int NT = K >> 5;

#define STG(slot, kt)                                                          \
  { _Pragma("unroll")                                                          \
    for (int i = 0; i < 2; ++i) {                                              \
      GLOAD16(gA + (size_t)(i * 64) * K + (kt) * 32, &sA[slot][i * 2048 + wave * 512]); \
      GLOAD16(gB + (size_t)(i * 64) * K + (kt) * 32, &sB[slot][i * 2048 + wave * 512]); \
    } }

  STG(0, 0);
  STG(1, 1);
  int sl = 0;
  for (int t = 0; t < NT; ++t) {
    if (t < NT - 1) asm volatile("s_waitcnt vmcnt(4)" ::: "memory");
    else            asm volatile("s_waitcnt vmcnt(0)" ::: "memory");
    __builtin_amdgcn_s_barrier();
    __builtin_amdgcn_sched_barrier(0);
    if (t + 2 < NT) {
      int sl2 = sl - 1; if (sl2 < 0) sl2 = 2;
      STG(sl2, t + 2);
    }
    s16x8 av[4], bv[4];
#pragma unroll
    for (int m = 0; m < 4; ++m) av[m] = *(const s16x8*)&sA[sl][baseA + m * 512];
#pragma unroll
    for (int n = 0; n < 4; ++n) bv[n] = *(const s16x8*)&sB[sl][baseB + n * 512];
    __builtin_amdgcn_s_setprio(1);
#pragma unroll
    for (int m = 0; m < 4; ++m)
#pragma unroll
      for (int n = 0; n < 4; ++n)
        acc[m][n] = __builtin_amdgcn_mfma_f32_16x16x32_bf16(bv[n], av[m], acc[m][n], 0, 0, 0);
    __builtin_amdgcn_s_setprio(0);
    asm volatile("s_waitcnt lgkmcnt(0)" ::: "memory");
    sl = (sl == 2) ? 0 : sl + 1;
  }
#undef STG

  const int orow_ = bm + wr + lrow;
  const int ocol_ = bn + wc + g * 4;
#pragma unroll
  for (int m = 0; m < 4; ++m)
#pragma unroll
    for (int n = 0; n < 4; ++n)
      epi_store<RES, GELU, OUTBF, KVT>(acc[m][n], orow_ + m * 16, ocol_ + n * 16,
                                       bias, res, outp, N);
}

// ---------------- windowed (WS=3) attention, thread per (side-pos, head, q-row) ----------------
__global__ __launch_bounds__(256) void winattn(const unsigned short* __restrict__ qkv,
                                               unsigned short* __restrict__ o) {
  int g = blockIdx.x * 256 + threadIdx.x;
  if (g >= 4096 * 48) return;
  int i = g % 3;
  int t = g / 3;
  int h = t & 15;
  int sp = t >> 4;
  const unsigned short* base = qkv + (size_t)sp * 4608 + h * 32;
  float qv[32];
  {
    const u16x8* qp = (const u16x8*)(base + (size_t)i * 1536);
#pragma unroll
    for (int c = 0; c < 4; ++c) {
      u16x8 v = qp[c];
#pragma unroll
      for (int j = 0; j < 8; ++j) qv[c * 8 + j] = b2f(v[j]);
    }
  }
  float s[3];
#pragma unroll
  for (int j3 = 0; j3 < 3; ++j3) {
    const u16x8* kp = (const u16x8*)(base + (size_t)j3 * 1536 + 512);
    float acc = 0.f;
#pragma unroll
    for (int c = 0; c < 4; ++c) {
      u16x8 v = kp[c];
#pragma unroll
      for (int j = 0; j < 8; ++j) acc += qv[c * 8 + j] * b2f(v[j]);
    }
    s[j3] = acc * 0.17677669529663687f;
  }
  float mx = fmaxf(s[0], fmaxf(s[1], s[2]));
  float e0 = __expf(s[0] - mx), e1 = __expf(s[1] - mx), e2 = __expf(s[2] - mx);
  float inv = 1.0f / (e0 + e1 + e2);
  float a0 = e0 * inv, a1 = e1 * inv, a2 = e2 * inv;
  unsigned short* op = o + (size_t)(sp * 3 + i) * 512 + h * 32;
  const u16x8* v0p = (const u16x8*)(base + 1024);
  const u16x8* v1p = (const u16x8*)(base + 1536 + 1024);
  const u16x8* v2p = (const u16x8*)(base + 3072 + 1024);
#pragma unroll
  for (int c = 0; c < 4; ++c) {
    u16x8 x0 = v0p[c], x1 = v1p[c], x2 = v2p[c];
    u16x8 ov;
#pragma unroll
    for (int j = 0; j < 8; ++j)
      ov[j] = f2b(a0 * b2f(x0[j]) + a1 * b2f(x1[j]) + a2 * b2f(x2[j]));
    *(u16x8*)(op + c * 8) = ov;
  }
}

// ---------------- cross attention, MFMA flash style; BOTH sides per (b,h) block ----------------
__global__ __launch_bounds__(512) void crossattn_mfma(const unsigned short* __restrict__ q,
    const unsigned short* __restrict__ Kp, const unsigned short* __restrict__ VpT,
    unsigned short* __restrict__ o) {
  __shared__ unsigned short Plds[8][2][16 * 40];
  const int bh = blockIdx.x;
  const int b = bh >> 4, h = bh & 15;
  const int tid = threadIdx.x;
  const int w = tid >> 6, lane = tid & 63;
  const int side = w >> 2, wsub = w & 3;
  const int ql = lane & 15, g = lane >> 4;
  const int qrow = side * 2048 + b * 64 + wsub * 16 + ql;
  const float SC = 0.17677669529663687f;
  s16x8 qf;
  {
    u16x8 qv8 = *(const u16x8*)(q + (size_t)qrow * 512 + h * 32 + g * 8);
#pragma unroll
    for (int j = 0; j < 8; ++j) qf[j] = (short)f2b(b2f(qv8[j]) * SC);
  }
  const unsigned short* kbase = Kp + ((size_t)(b * 16 + h) * 1024) * 32;
  const unsigned short* vbase = VpT + ((size_t)(b * 16 + h) * 32) * 1024;
  f32x4 oacc0 = {}, oacc1 = {};
  float m_run = -1e30f, l_part = 0.f;
  for (int kv0 = 0; kv0 < 1024; kv0 += 32) {
    const int pp = (kv0 >> 5) & 1;
    s16x8 kf0 = *(const s16x8*)(kbase + (size_t)(kv0 + ql) * 32 + g * 8);
    s16x8 kf1 = *(const s16x8*)(kbase + (size_t)(kv0 + 16 + ql) * 32 + g * 8);
    f32x4 z = {0.f, 0.f, 0.f, 0.f};
    f32x4 s0 = __builtin_amdgcn_mfma_f32_16x16x32_bf16(kf0, qf, z, 0, 0, 0);
    f32x4 s1 = __builtin_amdgcn_mfma_f32_16x16x32_bf16(kf1, qf, z, 0, 0, 0);
    float cm = fmaxf(fmaxf(fmaxf(s0[0], s0[1]), fmaxf(s0[2], s0[3])),
                     fmaxf(fmaxf(s1[0], s1[1]), fmaxf(s1[2], s1[3])));
    cm = fmaxf(cm, __shfl_xor(cm, 16));
    cm = fmaxf(cm, __shfl_xor(cm, 32));
    float m_new = fmaxf(m_run, cm);
    float corr = __expf(m_run - m_new);
    m_run = m_new;
    float p0[4], p1[4], ps = 0.f;
#pragma unroll
    for (int r = 0; r < 4; ++r) {
      p0[r] = __expf(s0[r] - m_new);
      p1[r] = __expf(s1[r] - m_new);
      ps += p0[r] + p1[r];
    }
    l_part = l_part * corr + ps;
    oacc0 *= corr; oacc1 *= corr;
    u16x4 w0, w1;
#pragma unroll
    for (int r = 0; r < 4; ++r) { w0[r] = f2b(p0[r]); w1[r] = f2b(p1[r]); }
    *(u16x4*)&Plds[w][pp][ql * 40 + g * 4] = w0;
    *(u16x4*)&Plds[w][pp][ql * 40 + 16 + g * 4] = w1;
    __syncthreads();
    s16x8 pf = *(const s16x8*)&Plds[w][pp][ql * 40 + g * 8];
    s16x8 vf0 = *(const s16x8*)(vbase + (size_t)ql * 1024 + kv0 + g * 8);
    s16x8 vf1 = *(const s16x8*)(vbase + (size_t)(16 + ql) * 1024 + kv0 + g * 8);
    oacc0 = __builtin_amdgcn_mfma_f32_16x16x32_bf16(vf0, pf, oacc0, 0, 0, 0);
    oacc1 = __builtin_amdgcn_mfma_f32_16x16x32_bf16(vf1, pf, oacc1, 0, 0, 0);
  }
  float lf = l_part;
  lf += __shfl_xor(lf, 16);
  lf += __shfl_xor(lf, 32);
  float inv = 1.0f / lf;
  unsigned short* op = o + (size_t)qrow * 512 + h * 32;
  u16x4 ov0, ov1;
#pragma unroll
  for (int r = 0; r < 4; ++r) {
    ov0[r] = f2b(oacc0[r] * inv);
    ov1[r] = f2b(oacc1[r] * inv);
  }
  *(u16x4*)(op + g * 4) = ov0;
  *(u16x4*)(op + 16 + g * 4) = ov1;
}

extern "C" void kernel_launch(void* const* d_in, const int* in_sizes, int n_in,
                              void* d_out, int out_size, void* d_ws, size_t ws_size,
                              hipStream_t stream) {
  const float* visual   = (const float*)d_in[0];
  const int*   targets  = (const int*)d_in[1];
  const int*   pad_p    = (const int*)d_in[2];
  const float* char_emb = (const float*)d_in[3];
  const float* ln1_g = (const float*)d_in[4];
  const float* ln1_b = (const float*)d_in[5];
  const float* in_proj_w = (const float*)d_in[6];
  const float* in_proj_b = (const float*)d_in[7];
  const float* out_w = (const float*)d_in[8];
  const float* out_b = (const float*)d_in[9];
  const float* fc1_w = (const float*)d_in[10];
  const float* fc1_b = (const float*)d_in[11];
  const float* fc2_w = (const float*)d_in[12];
  const float* fc2_b = (const float*)d_in[13];
  const float* ln2_g = (const float*)d_in[14];
  const float* ln2_b = (const float*)d_in[15];
  const float* ltok  = (const float*)d_in[16];
  const float* rtok  = (const float*)d_in[17];
  const float* q_w   = (const float*)d_in[18];
  const float* q_b   = (const float*)d_in[19];
  const float* kv_w  = (const float*)d_in[20];
  const float* kv_b  = (const float*)d_in[21];
  const float* proj_w = (const float*)d_in[22];
  const float* proj_b = (const float*)d_in[23];
  const float* lnq_g = (const float*)d_in[24];
  const float* lnq_b = (const float*)d_in[25];
  const float* lnkv_g = (const float*)d_in[26];
  const float* lnkv_b = (const float*)d_in[27];
  const float* head_w = (const float*)d_in[28];
  const float* head_b = (const float*)d_in[29];

  // workspace layout (bytes); Kp+VpT (bf16, 67MB) alias the dead encoder region
  char* ws = (char*)d_ws;
  unsigned short* W    = (unsigned short*)ws;                    // 14,680,064 B weights bf16
  unsigned short* XB   = (unsigned short*)(ws + 14680064ull);    // 12,582,912 B x bf16 12288x512
  unsigned short* KP   = (unsigned short*)(ws + 14680064ull);    // alias: 33,554,432 B Kp + 33,554,432 B VpT
  unsigned short* A1   = (unsigned short*)(ws + 39845888ull);    // 12,582,912 B bf16 12288x512
  unsigned short* B1   = (unsigned short*)(ws + 52428800ull);    // 25,165,824 B bf16 12288x1024
  unsigned short* QKV  = (unsigned short*)(ws + 77594624ull);    // 37,748,736 B bf16 12288x1536
  float*          ENC  = (float*)(ws + 115343360ull);            //  8,388,608 B fp32 4096x512
  unsigned short* VIS  = (unsigned short*)(ws + 123731968ull);   // 33,554,432 B bf16 32768x512
  unsigned short* Q    = (unsigned short*)(ws + 157286400ull);   //  4,194,304 B bf16 4096x512
  unsigned short* OC   = (unsigned short*)(ws + 165675008ull);   //  4,194,304 B bf16 4096x512
  unsigned short* FEAT = (unsigned short*)(ws + 169869312ull);   //  4,194,304 B bf16 4096x512
  unsigned short* LNQ  = (unsigned short*)(ws + 174063616ull);   //  4,194,304 B bf16 4096x512
  unsigned short* VPT  = KP + 16777216u;

  unsigned short* Wip   = W;
  unsigned short* Wout  = W + 786432;
  unsigned short* Wfc1  = W + 1048576;
  unsigned short* Wfc2  = W + 1572864;
  unsigned short* Wq    = W + 2097152;
  unsigned short* Wkv   = W + 2359296;
  unsigned short* Wproj = W + 2883584;
  unsigned short* Whead = W + 3145728;

  // one fused convert for all 8 weight matrices (1,835,008 float4 chunks)
  cvt_all<<<dim3(7168), dim3(256), 0, stream>>>(in_proj_w, out_w, fc1_w, fc2_w,
                                                q_w, kv_w, proj_w, head_w, W);

  // ---- encoders (left+right batched, M=12288) ----
  embed_ln1<<<dim3(3072), dim3(256), 0, stream>>>(targets, pad_p, char_emb, ltok, rtok,
                                                  ln1_g, ln1_b, XB, A1);
  gemm128<0,0,1,0><<<dim3(12, 96), dim3(256), 0, stream>>>(A1, Wip, in_proj_b, nullptr, QKV, 12288, 1536, 512);
  winattn<<<dim3(768), dim3(256), 0, stream>>>(QKV, B1);
  gemm128<2,0,1,0><<<dim3(4, 96), dim3(256), 0, stream>>>(B1, Wout, out_b, XB, XB, 12288, 512, 512);
  ln_rows<1><<<dim3(3072), dim3(256), 0, stream>>>(XB, ln2_g, ln2_b, A1, 12288);
  gemm128<0,1,1,0><<<dim3(8, 96), dim3(256), 0, stream>>>(A1, Wfc1, fc1_b, nullptr, B1, 12288, 1024, 512);
  gemm128<2,0,1,0><<<dim3(4, 96), dim3(256), 0, stream>>>(B1, Wfc2, fc2_b, XB, XB, 12288, 512, 1024);
  mean3_lnq<<<dim3(1024), dim3(256), 0, stream>>>(XB, lnq_g, lnq_b, ENC, LNQ,
                                                  targets, (float*)d_out + 33554432);

  // ---- cross attention (kv shared by both sides; encoder buffers now dead) ----
  ln_rows<0><<<dim3(8192), dim3(256), 0, stream>>>(visual, lnkv_g, lnkv_b, VIS, 32768);
  gemm128<0,0,1,1><<<dim3(8, 256), dim3(256), 0, stream>>>(VIS, Wkv, kv_b, nullptr, KP, 32768, 1024, 512);
  gemm128<0,0,1,0><<<dim3(4, 32), dim3(256), 0, stream>>>(LNQ, Wq, q_b, nullptr, Q, 4096, 512, 512);
  crossattn_mfma<<<dim3(512), dim3(512), 0, stream>>>(Q, KP, VPT, OC);
  gemm128<1,0,1,0><<<dim3(4, 32), dim3(256), 0, stream>>>(OC, Wproj, proj_b, ENC, FEAT, 4096, 512, 512);

  // ---- head -> d_out (rows 0..2047 = sgm_left, 2048..4095 = sgm_right) ----
  gemm128<0,0,0,0><<<dim3(64, 32), dim3(256), 0, stream>>>(FEAT, Whead, head_b, nullptr, (float*)d_out, 4096, 8192, 512);
}

// Round 19
// 368.467 us; speedup vs baseline: 1.0893x; 1.0275x over previous
//
#include <hip/hip_runtime.h>
#include <hip/hip_bf16.h>
#include <cstdint>
#include <cstddef>

// SGM fused pipeline, MI355X gfx950.
// Shapes: B=32 L=64 N=1024 D=512 C=8192 WS=3 NH=16 HD=32 HID=1024
// Encoder rows M=12288 (side*6144 + pos*3 + w), cross rows 4096 (side*2048+pos).
// Residual stream X and Q are bf16 (threshold headroom ~20000x).
// GEMMs: gemm128 (ring-3 counted-vmcnt, 3 blocks/CU) for the big shapes;
// gemm64x128 (same pipeline, 64x128 tile, 4 blocks/CU) for the four N=512
// launches, which were machine-underfilled (q/proj used only half the CUs).

typedef __attribute__((ext_vector_type(8))) short s16x8;
typedef __attribute__((ext_vector_type(8))) unsigned short u16x8;
typedef __attribute__((ext_vector_type(4))) unsigned short u16x4;
typedef __attribute__((ext_vector_type(4))) float f32x4;

__device__ __forceinline__ float b2f(unsigned short u) {
  union { unsigned int i; float f; } c; c.i = ((unsigned int)u) << 16; return c.f;
}
__device__ __forceinline__ unsigned short f2b(float f) {
  union { float f; unsigned int i; } c; c.f = f;
  unsigned int x = c.i;
  return (unsigned short)((x + 0x7FFFu + ((x >> 16) & 1u)) >> 16); // RNE, no NaN in this net
}

// async global->LDS, 16B per lane; LDS dest is wave-uniform base + lane*16
#define GLOAD16(gp, lp)                                                        \
  __builtin_amdgcn_global_load_lds(                                           \
      (const __attribute__((address_space(1))) void*)(gp),                    \
      (__attribute__((address_space(3))) void*)(lp), 16, 0, 0)

// ---------------- fused fp32 -> bf16 convert for ALL weights (1 launch) ----------------
__global__ void cvt_all(const float* __restrict__ s0, const float* __restrict__ s1,
                        const float* __restrict__ s2, const float* __restrict__ s3,
                        const float* __restrict__ s4, const float* __restrict__ s5,
                        const float* __restrict__ s6, const float* __restrict__ s7,
                        unsigned short* __restrict__ d) {
  int c = blockIdx.x * 256 + threadIdx.x;
  if (c >= 1835008) return;
  int e = c * 4;
  const float* sp; int off;
  if      (e <  786432) { sp = s0; off = 0; }
  else if (e < 1048576) { sp = s1; off =  786432; }
  else if (e < 1572864) { sp = s2; off = 1048576; }
  else if (e < 2097152) { sp = s3; off = 1572864; }
  else if (e < 2359296) { sp = s4; off = 2097152; }
  else if (e < 2883584) { sp = s5; off = 2359296; }
  else if (e < 3145728) { sp = s6; off = 2883584; }
  else                  { sp = s7; off = 3145728; }
  float4 v = *(const float4*)(sp + (e - off));
  u16x4 o; o[0] = f2b(v.x); o[1] = f2b(v.y); o[2] = f2b(v.z); o[3] = f2b(v.w);
  *(u16x4*)(d + e) = o;
}

// ---------------- FUSED embed + token + LN1 (wave per row; id is row-uniform) -----------
__global__ __launch_bounds__(256) void embed_ln1(const int* __restrict__ targets,
    const int* __restrict__ pad_p, const float* __restrict__ ce,
    const float* __restrict__ ltok, const float* __restrict__ rtok,
    const float* __restrict__ g, const float* __restrict__ bb,
    unsigned short* __restrict__ xb, unsigned short* __restrict__ a1) {
  int row = blockIdx.x * 4 + (threadIdx.x >> 6);   // 0..12287
  int lane = threadIdx.x & 63;
  int side = row >= 6144;
  int rem = row - side * 6144;
  int pos = rem / 3, w = rem - pos * 3;
  int b = pos >> 6, l = pos & 63;
  int id;
  if (!side) { int ti = l + w - 3; id = (ti >= 0) ? targets[(b << 6) + ti] : *pad_p; }
  else       { int ti = l + w + 1; id = (ti < 64) ? targets[(b << 6) + ti] : *pad_p; }
  const float* cp = ce + (size_t)id * 512 + lane * 8;
  const float* tp = (side ? rtok : ltok) + lane * 8;
  float4 c0 = ((const float4*)cp)[0], c1 = ((const float4*)cp)[1];
  float4 t0 = ((const float4*)tp)[0], t1 = ((const float4*)tp)[1];
  float vv[8] = {c0.x + t0.x, c0.y + t0.y, c0.z + t0.z, c0.w + t0.w,
                 c1.x + t1.x, c1.y + t1.y, c1.z + t1.z, c1.w + t1.w};
  int c = lane * 8;
  u16x8 xo;
#pragma unroll
  for (int j = 0; j < 8; ++j) xo[j] = f2b(vv[j]);
  *(u16x8*)(xb + (size_t)row * 512 + c) = xo;
  float s = 0.f, ss = 0.f;
#pragma unroll
  for (int j = 0; j < 8; ++j) { s += vv[j]; ss += vv[j] * vv[j]; }
#pragma unroll
  for (int o = 1; o < 64; o <<= 1) { s += __shfl_xor(s, o); ss += __shfl_xor(ss, o); }
  float mean = s * (1.0f / 512.0f);
  float var = ss * (1.0f / 512.0f) - mean * mean;
  float inv = rsqrtf(var + 1e-5f);
  u16x8 o8;
#pragma unroll
  for (int j = 0; j < 8; ++j) o8[j] = f2b((vv[j] - mean) * inv * g[c + j] + bb[c + j]);
  *(u16x8*)(a1 + (size_t)row * 512 + c) = o8;
}

// ---------------- LayerNorm (D=512 -> bf16 out), one wave per row; INBF: input dtype ----
template<int INBF>
__global__ __launch_bounds__(256) void ln_rows(const void* __restrict__ in,
    const float* __restrict__ g, const float* __restrict__ b,
    unsigned short* __restrict__ out, int M) {
  int row = blockIdx.x * 4 + (threadIdx.x >> 6);
  int lane = threadIdx.x & 63;
  float vv[8];
  if (INBF) {
    u16x8 v8 = *(const u16x8*)((const unsigned short*)in + (size_t)row * 512 + lane * 8);
#pragma unroll
    for (int j = 0; j < 8; ++j) vv[j] = b2f(v8[j]);
  } else {
    const float* rp = (const float*)in + (size_t)row * 512;
    float4 v0 = ((const float4*)rp)[lane * 2];
    float4 v1 = ((const float4*)rp)[lane * 2 + 1];
    vv[0] = v0.x; vv[1] = v0.y; vv[2] = v0.z; vv[3] = v0.w;
    vv[4] = v1.x; vv[5] = v1.y; vv[6] = v1.z; vv[7] = v1.w;
  }
  float s = 0.f, ss = 0.f;
#pragma unroll
  for (int j = 0; j < 8; ++j) { s += vv[j]; ss += vv[j] * vv[j]; }
#pragma unroll
  for (int o = 1; o < 64; o <<= 1) { s += __shfl_xor(s, o); ss += __shfl_xor(ss, o); }
  float mean = s * (1.0f / 512.0f);
  float var = ss * (1.0f / 512.0f) - mean * mean;
  float inv = rsqrtf(var + 1e-5f);
  int c = lane * 8;
  u16x8 o8;
#pragma unroll
  for (int j = 0; j < 8; ++j) o8[j] = f2b((vv[j] - mean) * inv * g[c + j] + b[c + j]);
  *(u16x8*)(out + (size_t)row * 512 + c) = o8;
}

// ---------------- FUSED mean over WS=3 + LNq (+ targets pass-through) ----------------
__global__ __launch_bounds__(256) void mean3_lnq(const unsigned short* __restrict__ x,
    const float* __restrict__ g, const float* __restrict__ bb,
    float* __restrict__ enc, unsigned short* __restrict__ lnq,
    const int* __restrict__ targets, float* __restrict__ out2) {
  int fid = blockIdx.x * 256 + threadIdx.x;
  if (fid < 2048) out2[fid] = (float)targets[fid];
  int p = blockIdx.x * 4 + (threadIdx.x >> 6);   // 0..4095
  int lane = threadIdx.x & 63;
  int c = lane * 8;
  u16x8 a = *(const u16x8*)(x + ((size_t)(p * 3 + 0) * 512 + c));
  u16x8 b = *(const u16x8*)(x + ((size_t)(p * 3 + 1) * 512 + c));
  u16x8 d = *(const u16x8*)(x + ((size_t)(p * 3 + 2) * 512 + c));
  float vv[8];
#pragma unroll
  for (int j = 0; j < 8; ++j) vv[j] = (b2f(a[j]) + b2f(b[j]) + b2f(d[j])) * (1.0f / 3.0f);
  float4 e0, e1;
  e0.x = vv[0]; e0.y = vv[1]; e0.z = vv[2]; e0.w = vv[3];
  e1.x = vv[4]; e1.y = vv[5]; e1.z = vv[6]; e1.w = vv[7];
  float* ep = enc + (size_t)p * 512 + c;
  ((float4*)ep)[0] = e0; ((float4*)ep)[1] = e1;
  float s = 0.f, ss = 0.f;
#pragma unroll
  for (int j = 0; j < 8; ++j) { s += vv[j]; ss += vv[j] * vv[j]; }
#pragma unroll
  for (int o = 1; o < 64; o <<= 1) { s += __shfl_xor(s, o); ss += __shfl_xor(ss, o); }
  float mean = s * (1.0f / 512.0f);
  float var = ss * (1.0f / 512.0f) - mean * mean;
  float inv = rsqrtf(var + 1e-5f);
  u16x8 o8;
#pragma unroll
  for (int j = 0; j < 8; ++j) o8[j] = f2b((vv[j] - mean) * inv * g[c + j] + bb[c + j]);
  *(u16x8*)(lnq + (size_t)p * 512 + c) = o8;
}

// ======== shared epilogue (wide stores; swapped-operand C layout) ========
template<int RES, int GELU, int OUTBF, int KVT>
__device__ __forceinline__ void epi_store(f32x4 v, int row, int col,
    const float* __restrict__ bias, const void* __restrict__ res,
    void* __restrict__ outp, int N) {
  f32x4 b4 = *(const f32x4*)(bias + col);
  v += b4;
  if (GELU) {
#pragma unroll
    for (int r = 0; r < 4; ++r)
      v[r] = 0.5f * v[r] * (1.0f + erff(v[r] * 0.70710678118654752f));
  }
  if (RES == 1) v += *(const f32x4*)((const float*)res + (size_t)row * N + col);
  if (RES == 2) {
    u16x4 r4 = *(const u16x4*)((const unsigned short*)res + (size_t)row * N + col);
#pragma unroll
    for (int r = 0; r < 4; ++r) v[r] += b2f(r4[r]);
  }
  if (KVT) {
    // row = b*1024 + n_vis ; col<512 -> K head block (contig dd), col>=512 -> V^T
    int bb = row >> 10, nn = row & 1023;
    unsigned short* Kp = (unsigned short*)outp;
    unsigned short* VpT = Kp + 16777216u;
    if (col < 512) {
      int hh = col >> 5, dd = col & 31;
      u16x4 o4;
#pragma unroll
      for (int r = 0; r < 4; ++r) o4[r] = f2b(v[r]);
      *(u16x4*)(Kp + (((size_t)(bb * 16 + hh)) * 1024 + nn) * 32 + dd) = o4;
    } else {
      int cc = col - 512, hh = cc >> 5, dd = cc & 31;
#pragma unroll
      for (int r = 0; r < 4; ++r)
        VpT[(((size_t)(bb * 16 + hh)) * 32 + dd + r) * 1024 + nn] = f2b(v[r]);
    }
  } else if (OUTBF) {
    u16x4 o4;
#pragma unroll
    for (int r = 0; r < 4; ++r) o4[r] = f2b(v[r]);
    *(u16x4*)((unsigned short*)outp + (size_t)row * N + col) = o4;
  } else {
    *(f32x4*)((float*)outp + (size_t)row * N + col) = v;
  }
}

// ---------------- bf16 MFMA GEMM, 128x128, BK=32, 3-slot ring, 3 blocks/CU -------
// Prefetch-distance-2 ring; one raw s_barrier/step; counted vmcnt(4); trailing
// lgkmcnt(0) fences slot reuse. launch_bounds(256,3): 144 regs/thread = 3 waves/SIMD;
// LDS 3x48KB fits 3 blocks/CU. Row-pair XOR swizzle (conflict-free, measured 0);
// swapped-operand MFMA -> wide stores; col-fastest order; bijective XCD swizzle.
template<int RES, int GELU, int OUTBF, int KVT>
__global__ __launch_bounds__(256, 3) void gemm128(
    const unsigned short* __restrict__ A, const unsigned short* __restrict__ Bt,
    const float* __restrict__ bias, const void* __restrict__ res,
    void* __restrict__ outp, int M, int N, int K) {
  __shared__ unsigned short sA[3][4096];
  __shared__ unsigned short sB[3][4096];
  const int tid = threadIdx.x;
  const int nbx = gridDim.x;
  int id = blockIdx.y * nbx + blockIdx.x;
  {
    const int nwg = nbx * gridDim.y;
    if ((nwg & 7) == 0) id = (id & 7) * (nwg >> 3) + (id >> 3);
  }
  const int bm = (id / nbx) * 128, bn = (id % nbx) * 128;
  const int wave = tid >> 6, lane = tid & 63;
  const int wr = (wave >> 1) * 64, wc = (wave & 1) * 64;
  const int lrow = lane & 15, g = lane >> 4;
  f32x4 acc[4][4] = {};
  const int xoff = (((((lrow & 1) << 2) | g) ^ ((lrow >> 1) & 7)) << 3);
  const int baseA = ((wr >> 1) + (lrow >> 1)) * 64 + xoff;
  const int baseB = ((wc >> 1) + (lrow >> 1)) * 64 + xoff;
  const int slot8 = (tid & 7) ^ ((tid >> 3) & 7);
  const int srow = ((tid >> 3) << 1) + (slot8 >> 2);
  const int scol = (slot8 & 3) << 3;
  const unsigned short* gA = A + (size_t)(bm + srow) * K + scol;
  const unsigned short* gB = Bt + (size_t)(bn + srow) * K + scol;
  const int NT = K >> 5;

#define STG(slot, kt)                                                          \
  { _Pragma("unroll")                                                          \
    for (int i = 0; i < 2; ++i) {                                              \
      GLOAD16(gA + (size_t)(i * 64) * K + (kt) * 32, &sA[slot][i * 2048 + wave * 512]); \
      GLOAD16(gB + (size_t)(i * 64) * K + (kt) * 32, &sB[slot][i * 2048 + wave * 512]); \
    } }

  STG(0, 0);
  STG(1, 1);
  int sl = 0;
  for (int t = 0; t < NT; ++t) {
    if (t < NT - 1) asm volatile("s_waitcnt vmcnt(4)" ::: "memory");
    else            asm volatile("s_waitcnt vmcnt(0)" ::: "memory");
    __builtin_amdgcn_s_barrier();
    __builtin_amdgcn_sched_barrier(0);
    if (t + 2 < NT) {
      int sl2 = sl - 1; if (sl2 < 0) sl2 = 2;
      STG(sl2, t + 2);
    }
    s16x8 av[4], bv[4];
#pragma unroll
    for (int m = 0; m < 4; ++m) av[m] = *(const s16x8*)&sA[sl][baseA + m * 512];
#pragma unroll
    for (int n = 0; n < 4; ++n) bv[n] = *(const s16x8*)&sB[sl][baseB + n * 512];
    __builtin_amdgcn_s_setprio(1);
#pragma unroll
    for (int m = 0; m < 4; ++m)
#pragma unroll
      for (int n = 0; n < 4; ++n)
        acc[m][n] = __builtin_amdgcn_mfma_f32_16x16x32_bf16(bv[n], av[m], acc[m][n], 0, 0, 0);
    __builtin_amdgcn_s_setprio(0);
    asm volatile("s_waitcnt lgkmcnt(0)" ::: "memory");
    sl = (sl == 2) ? 0 : sl + 1;
  }
#undef STG

  const int orow_ = bm + wr + lrow;
  const int ocol_ = bn + wc + g * 4;
#pragma unroll
  for (int m = 0; m < 4; ++m)
#pragma unroll
    for (int n = 0; n < 4; ++n)
      epi_store<RES, GELU, OUTBF, KVT>(acc[m][n], orow_ + m * 16, ocol_ + n * 16,
                                       bias, res, outp, N);
}

// ---------------- bf16 MFMA GEMM, 64x128 tile, BK=32, ring-3, 4 blocks/CU ----------
// Same proven pipeline as gemm128 (distance-2 ring, counted vmcnt(3), single barrier,
// row-pair swizzle) at a quarter-size tile for the N=512 GEMMs: grids x2 (out/fc2
// 384->768 blocks, q/proj 128->256) -> full-machine fill. 4 waves x (32x64) wave
// tile, acc[2][4]=32 AGPR; LDS 36KB; launch_bounds(256,4) = 4 blocks/CU.
template<int RES, int GELU, int OUTBF>
__global__ __launch_bounds__(256, 4) void gemm64(
    const unsigned short* __restrict__ A, const unsigned short* __restrict__ Bt,
    const float* __restrict__ bias, const void* __restrict__ res,
    void* __restrict__ outp, int M, int N, int K) {
  __shared__ unsigned short sA[3][2048];   // 64 rows x 32 cols, row-pair swizzled
  __shared__ unsigned short sB[3][4096];   // 128 rows x 32 cols
  const int tid = threadIdx.x;
  const int nbx = gridDim.x;
  int id = blockIdx.y * nbx + blockIdx.x;
  {
    const int nwg = nbx * gridDim.y;
    if ((nwg & 7) == 0) id = (id & 7) * (nwg >> 3) + (id >> 3);
  }
  const int bm = (id / nbx) * 64, bn = (id % nbx) * 128;
  const int wave = tid >> 6, lane = tid & 63;
  const int wr = (wave >> 1) * 32, wc = (wave & 1) * 64;   // wave tile 32x64
  const int lrow = lane & 15, g = lane >> 4;
  f32x4 acc[2][4] = {};
  const int xoff = (((((lrow & 1) << 2) | g) ^ ((lrow >> 1) & 7)) << 3);
  const int baseA = ((wr >> 1) + (lrow >> 1)) * 64 + xoff;
  const int baseB = ((wc >> 1) + (lrow >> 1)) * 64 + xoff;
  // staging (identical bijection, A restricted to its verified 64-row half)
  const int slot8 = (tid & 7) ^ ((tid >> 3) & 7);
  const int srow = ((tid >> 3) << 1) + (slot8 >> 2);   // 0..63 (+ i*64 for B)
  const int scol = (slot8 & 3) << 3;
  const unsigned short* gA = A + (size_t)(bm + srow) * K + scol;
  const unsigned short* gB = Bt + (size_t)(bn + srow) * K + scol;
  const int NT = K >> 5;

#define STG64(slot, kt)                                                        \
  { GLOAD16(gA + (kt) * 32, &sA[slot][wave * 512]);                            \
    _Pragma("unroll")                                                          \
    for (int i = 0; i < 2; ++i)                                                \
      GLOAD16(gB + (size_t)(i * 64) * K + (kt) * 32, &sB[slot][i * 2048 + wave * 512]); \
  }

  STG64(0, 0);
  STG64(1, 1);               // 6 loads in flight
  int sl = 0;
  for (int t = 0; t < NT; ++t) {
    if (t < NT - 1) asm volatile("s_waitcnt vmcnt(3)" ::: "memory"); // t's 3 retired
    else            asm volatile("s_waitcnt vmcnt(0)" ::: "memory");
    __builtin_amdgcn_s_barrier();
    __builtin_amdgcn_sched_barrier(0);
    if (t + 2 < NT) {
      int sl2 = sl - 1; if (sl2 < 0) sl2 = 2;
      STG64(sl2, t + 2);
    }
    s16x8 av[2], bv[4];
#pragma unroll
    for (int m = 0; m < 2; ++m) av[m] = *(const s16x8*)&sA[sl][baseA + m * 512];
#pragma unroll
    for (int n = 0; n < 4; ++n) bv[n] = *(const s16x8*)&sB[sl][baseB + n * 512];
    __builtin_amdgcn_s_setprio(1);
#pragma unroll
    for (int m = 0; m < 2; ++m)
#pragma unroll
      for (int n = 0; n < 4; ++n)
        acc[m][n] = __builtin_amdgcn_mfma_f32_16x16x32_bf16(bv[n], av[m], acc[m][n], 0, 0, 0);
    __builtin_amdgcn_s_setprio(0);
    asm volatile("s_waitcnt lgkmcnt(0)" ::: "memory");
    sl = (sl == 2) ? 0 : sl + 1;
  }
#undef STG64

  const int orow_ = bm + wr + lrow;
  const int ocol_ = bn + wc + g * 4;
#pragma unroll
  for (int m = 0; m < 2; ++m)
#pragma unroll
    for (int n = 0; n < 4; ++n)
      epi_store<RES, GELU, OUTBF, 0>(acc[m][n], orow_ + m * 16, ocol_ + n * 16,
                                     bias, res, outp, N);
}

// ---------------- windowed (WS=3) attention, thread per (side-pos, head, q-row) ----------------
__global__ __launch_bounds__(256) void winattn(const unsigned short* __restrict__ qkv,
                                               unsigned short* __restrict__ o) {
  int g = blockIdx.x * 256 + threadIdx.x;
  if (g >= 4096 * 48) return;
  int i = g % 3;
  int t = g / 3;
  int h = t & 15;
  int sp = t >> 4;
  const unsigned short* base = qkv + (size_t)sp * 4608 + h * 32;
  float qv[32];
  {
    const u16x8* qp = (const u16x8*)(base + (size_t)i * 1536);
#pragma unroll
    for (int c = 0; c < 4; ++c) {
      u16x8 v = qp[c];
#pragma unroll
      for (int j = 0; j < 8; ++j) qv[c * 8 + j] = b2f(v[j]);
    }
  }
  float s[3];
#pragma unroll
  for (int j3 = 0; j3 < 3; ++j3) {
    const u16x8* kp = (const u16x8*)(base + (size_t)j3 * 1536 + 512);
    float acc = 0.f;
#pragma unroll
    for (int c = 0; c < 4; ++c) {
      u16x8 v = kp[c];
#pragma unroll
      for (int j = 0; j < 8; ++j) acc += qv[c * 8 + j] * b2f(v[j]);
    }
    s[j3] = acc * 0.17677669529663687f;
  }
  float mx = fmaxf(s[0], fmaxf(s[1], s[2]));
  float e0 = __expf(s[0] - mx), e1 = __expf(s[1] - mx), e2 = __expf(s[2] - mx);
  float inv = 1.0f / (e0 + e1 + e2);
  float a0 = e0 * inv, a1 = e1 * inv, a2 = e2 * inv;
  unsigned short* op = o + (size_t)(sp * 3 + i) * 512 + h * 32;
  const u16x8* v0p = (const u16x8*)(base + 1024);
  const u16x8* v1p = (const u16x8*)(base + 1536 + 1024);
  const u16x8* v2p = (const u16x8*)(base + 3072 + 1024);
#pragma unroll
  for (int c = 0; c < 4; ++c) {
    u16x8 x0 = v0p[c], x1 = v1p[c], x2 = v2p[c];
    u16x8 ov;
#pragma unroll
    for (int j = 0; j < 8; ++j)
      ov[j] = f2b(a0 * b2f(x0[j]) + a1 * b2f(x1[j]) + a2 * b2f(x2[j]));
    *(u16x8*)(op + c * 8) = ov;
  }
}

// ---------------- cross attention, MFMA flash style; BOTH sides per (b,h) block ----------------
__global__ __launch_bounds__(512) void crossattn_mfma(const unsigned short* __restrict__ q,
    const unsigned short* __restrict__ Kp, const unsigned short* __restrict__ VpT,
    unsigned short* __restrict__ o) {
  __shared__ unsigned short Plds[8][2][16 * 40];
  const int bh = blockIdx.x;
  const int b = bh >> 4, h = bh & 15;
  const int tid = threadIdx.x;
  const int w = tid >> 6, lane = tid & 63;
  const int side = w >> 2, wsub = w & 3;
  const int ql = lane & 15, g = lane >> 4;
  const int qrow = side * 2048 + b * 64 + wsub * 16 + ql;
  const float SC = 0.17677669529663687f;
  s16x8 qf;
  {
    u16x8 qv8 = *(const u16x8*)(q + (size_t)qrow * 512 + h * 32 + g * 8);
#pragma unroll
    for (int j = 0; j < 8; ++j) qf[j] = (short)f2b(b2f(qv8[j]) * SC);
  }
  const unsigned short* kbase = Kp + ((size_t)(b * 16 + h) * 1024) * 32;
  const unsigned short* vbase = VpT + ((size_t)(b * 16 + h) * 32) * 1024;
  f32x4 oacc0 = {}, oacc1 = {};
  float m_run = -1e30f, l_part = 0.f;
  for (int kv0 = 0; kv0 < 1024; kv0 += 32) {
    const int pp = (kv0 >> 5) & 1;
    s16x8 kf0 = *(const s16x8*)(kbase + (size_t)(kv0 + ql) * 32 + g * 8);
    s16x8 kf1 = *(const s16x8*)(kbase + (size_t)(kv0 + 16 + ql) * 32 + g * 8);
    f32x4 z = {0.f, 0.f, 0.f, 0.f};
    f32x4 s0 = __builtin_amdgcn_mfma_f32_16x16x32_bf16(kf0, qf, z, 0, 0, 0);
    f32x4 s1 = __builtin_amdgcn_mfma_f32_16x16x32_bf16(kf1, qf, z, 0, 0, 0);
    float cm = fmaxf(fmaxf(fmaxf(s0[0], s0[1]), fmaxf(s0[2], s0[3])),
                     fmaxf(fmaxf(s1[0], s1[1]), fmaxf(s1[2], s1[3])));
    cm = fmaxf(cm, __shfl_xor(cm, 16));
    cm = fmaxf(cm, __shfl_xor(cm, 32));
    float m_new = fmaxf(m_run, cm);
    float corr = __expf(m_run - m_new);
    m_run = m_new;
    float p0[4], p1[4], ps = 0.f;
#pragma unroll
    for (int r = 0; r < 4; ++r) {
      p0[r] = __expf(s0[r] - m_new);
      p1[r] = __expf(s1[r] - m_new);
      ps += p0[r] + p1[r];
    }
    l_part = l_part * corr + ps;
    oacc0 *= corr; oacc1 *= corr;
    u16x4 w0, w1;
#pragma unroll
    for (int r = 0; r < 4; ++r) { w0[r] = f2b(p0[r]); w1[r] = f2b(p1[r]); }
    *(u16x4*)&Plds[w][pp][ql * 40 + g * 4] = w0;
    *(u16x4*)&Plds[w][pp][ql * 40 + 16 + g * 4] = w1;
    __syncthreads();
    s16x8 pf = *(const s16x8*)&Plds[w][pp][ql * 40 + g * 8];
    s16x8 vf0 = *(const s16x8*)(vbase + (size_t)ql * 1024 + kv0 + g * 8);
    s16x8 vf1 = *(const s16x8*)(vbase + (size_t)(16 + ql) * 1024 + kv0 + g * 8);
    oacc0 = __builtin_amdgcn_mfma_f32_16x16x32_bf16(vf0, pf, oacc0, 0, 0, 0);
    oacc1 = __builtin_amdgcn_mfma_f32_16x16x32_bf16(vf1, pf, oacc1, 0, 0, 0);
  }
  float lf = l_part;
  lf += __shfl_xor(lf, 16);
  lf += __shfl_xor(lf, 32);
  float inv = 1.0f / lf;
  unsigned short* op = o + (size_t)qrow * 512 + h * 32;
  u16x4 ov0, ov1;
#pragma unroll
  for (int r = 0; r < 4; ++r) {
    ov0[r] = f2b(oacc0[r] * inv);
    ov1[r] = f2b(oacc1[r] * inv);
  }
  *(u16x4*)(op + g * 4) = ov0;
  *(u16x4*)(op + 16 + g * 4) = ov1;
}

extern "C" void kernel_launch(void* const* d_in, const int* in_sizes, int n_in,
                              void* d_out, int out_size, void* d_ws, size_t ws_size,
                              hipStream_t stream) {
  const float* visual   = (const float*)d_in[0];
  const int*   targets  = (const int*)d_in[1];
  const int*   pad_p    = (const int*)d_in[2];
  const float* char_emb = (const float*)d_in[3];
  const float* ln1_g = (const float*)d_in[4];
  const float* ln1_b = (const float*)d_in[5];
  const float* in_proj_w = (const float*)d_in[6];
  const float* in_proj_b = (const float*)d_in[7];
  const float* out_w = (const float*)d_in[8];
  const float* out_b = (const float*)d_in[9];
  const float* fc1_w = (const float*)d_in[10];
  const float* fc1_b = (const float*)d_in[11];
  const float* fc2_w = (const float*)d_in[12];
  const float* fc2_b = (const float*)d_in[13];
  const float* ln2_g = (const float*)d_in[14];
  const float* ln2_b = (const float*)d_in[15];
  const float* ltok  = (const float*)d_in[16];
  const float* rtok  = (const float*)d_in[17];
  const float* q_w   = (const float*)d_in[18];
  const float* q_b   = (const float*)d_in[19];
  const float* kv_w  = (const float*)d_in[20];
  const float* kv_b  = (const float*)d_in[21];
  const float* proj_w = (const float*)d_in[22];
  const float* proj_b = (const float*)d_in[23];
  const float* lnq_g = (const float*)d_in[24];
  const float* lnq_b = (const float*)d_in[25];
  const float* lnkv_g = (const float*)d_in[26];
  const float* lnkv_b = (const float*)d_in[27];
  const float* head_w = (const float*)d_in[28];
  const float* head_b = (const float*)d_in[29];

  // workspace layout (bytes); Kp+VpT (bf16, 67MB) alias the dead encoder region
  char* ws = (char*)d_ws;
  unsigned short* W    = (unsigned short*)ws;                    // 14,680,064 B weights bf16
  unsigned short* XB   = (unsigned short*)(ws + 14680064ull);    // 12,582,912 B x bf16 12288x512
  unsigned short* KP   = (unsigned short*)(ws + 14680064ull);    // alias: 33,554,432 B Kp + 33,554,432 B VpT
  unsigned short* A1   = (unsigned short*)(ws + 39845888ull);    // 12,582,912 B bf16 12288x512
  unsigned short* B1   = (unsigned short*)(ws + 52428800ull);    // 25,165,824 B bf16 12288x1024
  unsigned short* QKV  = (unsigned short*)(ws + 77594624ull);    // 37,748,736 B bf16 12288x1536
  float*          ENC  = (float*)(ws + 115343360ull);            //  8,388,608 B fp32 4096x512
  unsigned short* VIS  = (unsigned short*)(ws + 123731968ull);   // 33,554,432 B bf16 32768x512
  unsigned short* Q    = (unsigned short*)(ws + 157286400ull);   //  4,194,304 B bf16 4096x512
  unsigned short* OC   = (unsigned short*)(ws + 165675008ull);   //  4,194,304 B bf16 4096x512
  unsigned short* FEAT = (unsigned short*)(ws + 169869312ull);   //  4,194,304 B bf16 4096x512
  unsigned short* LNQ  = (unsigned short*)(ws + 174063616ull);   //  4,194,304 B bf16 4096x512
  unsigned short* VPT  = KP + 16777216u;

  unsigned short* Wip   = W;
  unsigned short* Wout  = W + 786432;
  unsigned short* Wfc1  = W + 1048576;
  unsigned short* Wfc2  = W + 1572864;
  unsigned short* Wq    = W + 2097152;
  unsigned short* Wkv   = W + 2359296;
  unsigned short* Wproj = W + 2883584;
  unsigned short* Whead = W + 3145728;

  // one fused convert for all 8 weight matrices (1,835,008 float4 chunks)
  cvt_all<<<dim3(7168), dim3(256), 0, stream>>>(in_proj_w, out_w, fc1_w, fc2_w,
                                                q_w, kv_w, proj_w, head_w, W);

  // ---- encoders (left+right batched, M=12288) ----
  embed_ln1<<<dim3(3072), dim3(256), 0, stream>>>(targets, pad_p, char_emb, ltok, rtok,
                                                  ln1_g, ln1_b, XB, A1);
  gemm128<0,0,1,0><<<dim3(12, 96), dim3(256), 0, stream>>>(A1, Wip, in_proj_b, nullptr, QKV, 12288, 1536, 512);
  winattn<<<dim3(768), dim3(256), 0, stream>>>(QKV, B1);
  gemm64<2,0,1><<<dim3(4, 192), dim3(256), 0, stream>>>(B1, Wout, out_b, XB, XB, 12288, 512, 512);
  ln_rows<1><<<dim3(3072), dim3(256), 0, stream>>>(XB, ln2_g, ln2_b, A1, 12288);
  gemm128<0,1,1,0><<<dim3(8, 96), dim3(256), 0, stream>>>(A1, Wfc1, fc1_b, nullptr, B1, 12288, 1024, 512);
  gemm64<2,0,1><<<dim3(4, 192), dim3(256), 0, stream>>>(B1, Wfc2, fc2_b, XB, XB, 12288, 512, 1024);
  mean3_lnq<<<dim3(1024), dim3(256), 0, stream>>>(XB, lnq_g, lnq_b, ENC, LNQ,
                                                  targets, (float*)d_out + 33554432);

  // ---- cross attention (kv shared by both sides; encoder buffers now dead) ----
  ln_rows<0><<<dim3(8192), dim3(256), 0, stream>>>(visual, lnkv_g, lnkv_b, VIS, 32768);
  gemm128<0,0,1,1><<<dim3(8, 256), dim3(256), 0, stream>>>(VIS, Wkv, kv_b, nullptr, KP, 32768, 1024, 512);
  gemm64<0,0,1><<<dim3(4, 64), dim3(256), 0, stream>>>(LNQ, Wq, q_b, nullptr, Q, 4096, 512, 512);
  crossattn_mfma<<<dim3(512), dim3(512), 0, stream>>>(Q, KP, VPT, OC);
  gemm64<1,0,1><<<dim3(4, 64), dim3(256), 0, stream>>>(OC, Wproj, proj_b, ENC, FEAT, 4096, 512, 512);

  // ---- head -> d_out (rows 0..2047 = sgm_left, 2048..4095 = sgm_right) ----
  gemm128<0,0,0,0><<<dim3(64, 32), dim3(256), 0, stream>>>(FEAT, Whead, head_b, nullptr, (float*)d_out, 4096, 8192, 512);
}